// Round 2
// baseline (1708.554 us; speedup 1.0000x reference)
//
#include <hip/hip_runtime.h>

static inline int ceil_div(long long a, long long b) { return (int)((a + b - 1) / b); }

// ---------- degree / normalization ----------
__global__ void zero_kernel(float* __restrict__ p, int n) {
    int i = blockIdx.x * 256 + threadIdx.x;
    if (i < n) p[i] = 0.0f;
}

__global__ void deg_kernel(const int* __restrict__ dst, const float* __restrict__ w,
                           float* __restrict__ deg, int E) {
    int e = blockIdx.x * 256 + threadIdx.x;
    if (e < E) atomicAdd(deg + dst[e], w[e]);
}

__global__ void dinv_kernel(float* __restrict__ deg, int N) {
    int i = blockIdx.x * 256 + threadIdx.x;
    if (i < N) deg[i] = rsqrtf(deg[i] + 1.0f);   // +1 = self-loop weight; always > 0
}

__global__ void norm_kernel(const int* __restrict__ src, const int* __restrict__ dst,
                            const float* __restrict__ w, const float* __restrict__ dinv,
                            float* __restrict__ norm, int E) {
    int e = blockIdx.x * 256 + threadIdx.x;
    if (e < E) norm[e] = dinv[src[e]] * w[e] * dinv[dst[e]];
}

// ---------- dense GEMMs (vector ALU; no fp32 MFMA on CDNA4) ----------
// H[N x 64] = X[N x 64] @ W[64 x 64]; 16 rows/block, 16 threads/row (4 cols each)
__global__ void gemm_64_64(const float* __restrict__ X, const float* __restrict__ W,
                           float* __restrict__ H, int N) {
    __shared__ float Ws[64 * 64];
    int tid = threadIdx.x;
    for (int i = tid; i < 64 * 64; i += 256) Ws[i] = W[i];
    __syncthreads();
    int row = blockIdx.x * 16 + (tid >> 4);
    if (row >= N) return;
    int cg = (tid & 15) << 2;
    const float4* xrow = (const float4*)(X + (long long)row * 64);
    float4 acc = make_float4(0.f, 0.f, 0.f, 0.f);
#pragma unroll
    for (int kk = 0; kk < 16; ++kk) {
        float4 xv = xrow[kk];
        float xs[4] = {xv.x, xv.y, xv.z, xv.w};
#pragma unroll
        for (int j = 0; j < 4; ++j) {
            const float* wr = Ws + (kk * 4 + j) * 64 + cg;
            acc.x += xs[j] * wr[0];
            acc.y += xs[j] * wr[1];
            acc.z += xs[j] * wr[2];
            acc.w += xs[j] * wr[3];
        }
    }
    ((float4*)(H + (long long)row * 64))[tid & 15] = acc;
}

// H[N x 32] = relu(X[N x 64]) @ W[64 x 32]; 32 rows/block, 8 threads/row
__global__ void gemm_relu_64_32(const float* __restrict__ X, const float* __restrict__ W,
                                float* __restrict__ H, int N) {
    __shared__ float Ws[64 * 32];
    int tid = threadIdx.x;
    for (int i = tid; i < 64 * 32; i += 256) Ws[i] = W[i];
    __syncthreads();
    int row = blockIdx.x * 32 + (tid >> 3);
    if (row >= N) return;
    int cg = (tid & 7) << 2;
    const float4* xrow = (const float4*)(X + (long long)row * 64);
    float4 acc = make_float4(0.f, 0.f, 0.f, 0.f);
#pragma unroll
    for (int kk = 0; kk < 16; ++kk) {
        float4 xv = xrow[kk];
        float xs[4] = {fmaxf(xv.x, 0.f), fmaxf(xv.y, 0.f), fmaxf(xv.z, 0.f), fmaxf(xv.w, 0.f)};
#pragma unroll
        for (int j = 0; j < 4; ++j) {
            const float* wr = Ws + (kk * 4 + j) * 32 + cg;
            acc.x += xs[j] * wr[0];
            acc.y += xs[j] * wr[1];
            acc.z += xs[j] * wr[2];
            acc.w += xs[j] * wr[3];
        }
    }
    ((float4*)(H + (long long)row * 32))[tid & 7] = acc;
}

// ---------- aggregation ----------
// out[i][:] = b[:] + dinv[i]^2 * h[i][:]   (bias + self-loop term; also zero-inits for atomics)
template <int C4>   // channel float4-groups per row: 16 (64ch) or 8 (32ch)
__global__ void init_out(const float* __restrict__ h, const float* __restrict__ dinv,
                         const float* __restrict__ b, float* __restrict__ out, int N) {
    unsigned t = blockIdx.x * 256 + threadIdx.x;
    if (t >= (unsigned)N * C4) return;
    unsigned row = t / C4;
    unsigned q = t & (C4 - 1);
    float di = dinv[row];
    float s = di * di;
    float4 hv = ((const float4*)h)[t];
    float4 bv = ((const float4*)b)[q];
    float4 o;
    o.x = bv.x + s * hv.x;
    o.y = bv.y + s * hv.y;
    o.z = bv.z + s * hv.z;
    o.w = bv.w + s * hv.w;
    ((float4*)out)[t] = o;
}

// out[dst[e]][:] += norm[e] * h[src[e]][:]  — one thread per (edge, 4 channels)
template <int CG>   // float4-groups per row: 16 (64ch) or 8 (32ch)
__global__ void scatter_add(const int* __restrict__ src, const int* __restrict__ dst,
                            const float* __restrict__ norm, const float* __restrict__ h,
                            float* __restrict__ out, int E) {
    unsigned t = blockIdx.x * 256 + threadIdx.x;
    unsigned e = t / CG;
    if (e >= (unsigned)E) return;
    unsigned q = t & (CG - 1);
    int s = src[e];
    int d = dst[e];
    float nm = norm[e];
    float4 hv = ((const float4*)h)[(unsigned)s * CG + q];
    float* o = out + ((unsigned)d * CG + q) * 4;
    atomicAdd(o + 0, hv.x * nm);
    atomicAdd(o + 1, hv.y * nm);
    atomicAdd(o + 2, hv.z * nm);
    atomicAdd(o + 3, hv.w * nm);
}

extern "C" void kernel_launch(void* const* d_in, const int* in_sizes, int n_in,
                              void* d_out, int out_size, void* d_ws, size_t ws_size,
                              hipStream_t stream) {
    const float* x   = (const float*)d_in[0];
    const int* eidx  = (const int*)d_in[1];     // int64 in reference -> int32 on device
    const float* w   = (const float*)d_in[2];
    const float* W1  = (const float*)d_in[3];
    const float* b1  = (const float*)d_in[4];
    const float* W2  = (const float*)d_in[5];
    const float* b2  = (const float*)d_in[6];
    float* out = (float*)d_out;

    const int E = in_sizes[2];
    const int N = in_sizes[0] / 64;
    const int* src = eidx;          // edge_index[0]
    const int* dst = eidx + E;      // edge_index[1]

    // workspace carve-up (256B-aligned): ~56.4 MB total
    char* ws = (char*)d_ws;
    size_t off = 0;
    auto alloc = [&](size_t bytes) -> void* {
        void* p = ws + off;
        off = (off + bytes + 255) & ~(size_t)255;
        return p;
    };
    float* dinv = (float*)alloc((size_t)N * 4);        // deg -> dinv in place
    float* norm = (float*)alloc((size_t)E * 4);
    float* bufA = (float*)alloc((size_t)N * 64 * 4);   // h1, then reused for h2
    float* bufB = (float*)alloc((size_t)N * 64 * 4);   // out1 (pre-relu)

    zero_kernel<<<ceil_div(N, 256), 256, 0, stream>>>(dinv, N);
    deg_kernel<<<ceil_div(E, 256), 256, 0, stream>>>(dst, w, dinv, E);
    dinv_kernel<<<ceil_div(N, 256), 256, 0, stream>>>(dinv, N);
    norm_kernel<<<ceil_div(E, 256), 256, 0, stream>>>(src, dst, w, dinv, norm, E);

    // layer 1: h1 = x@W1; out1 = b1 + dinv^2*h1 + scatter(norm*h1[src])
    gemm_64_64<<<ceil_div(N, 16), 256, 0, stream>>>(x, W1, bufA, N);
    init_out<16><<<ceil_div((long long)N * 16, 256), 256, 0, stream>>>(bufA, dinv, b1, bufB, N);
    scatter_add<16><<<ceil_div((long long)E * 16, 256), 256, 0, stream>>>(src, dst, norm, bufA, bufB, E);

    // layer 2: h2 = relu(out1)@W2; out = b2 + dinv^2*h2 + scatter(norm*h2[src])
    gemm_relu_64_32<<<ceil_div(N, 32), 256, 0, stream>>>(bufB, W2, bufA, N);
    init_out<8><<<ceil_div((long long)N * 8, 256), 256, 0, stream>>>(bufA, dinv, b2, out, N);
    scatter_add<8><<<ceil_div((long long)E * 8, 256), 256, 0, stream>>>(src, dst, norm, bufA, out, E);
}

// Round 3
// 496.441 us; speedup vs baseline: 3.4416x; 3.4416x over previous
//
#include <hip/hip_runtime.h>

static inline int ceil_div(long long a, long long b) { return (int)((a + b - 1) / b); }

// ---------------- CSR build ----------------
__global__ void zero_counts(int* __restrict__ cnt, float* __restrict__ degf, int N) {
    int i = blockIdx.x * 256 + threadIdx.x;
    if (i < N) { cnt[i] = 0; degf[i] = 0.f; }
}

__global__ void histogram(const int* __restrict__ dst, const float* __restrict__ w,
                          int* __restrict__ cnt, float* __restrict__ degf, int E) {
    int e = blockIdx.x * 256 + threadIdx.x;
    if (e < E) {
        int d = dst[e];
        atomicAdd(cnt + d, 1);
        atomicAdd(degf + d, w[e]);
    }
}

// per-256-block inclusive scan -> exclusive results + block sums
__global__ void scan1(const int* __restrict__ cnt, int* __restrict__ excl,
                      int* __restrict__ blockSums, int N) {
    __shared__ int s[256];
    int t = threadIdx.x;
    int i = blockIdx.x * 256 + t;
    int v = (i < N) ? cnt[i] : 0;
    s[t] = v;
    __syncthreads();
    for (int d = 1; d < 256; d <<= 1) {
        int add = (t >= d) ? s[t - d] : 0;
        __syncthreads();
        s[t] += add;
        __syncthreads();
    }
    if (i < N) excl[i] = s[t] - v;
    if (t == 255) blockSums[blockIdx.x] = s[t];
}

// single-block scan of block sums (nb <= 512)
__global__ void scan2(const int* __restrict__ blockSums, int* __restrict__ blockOffs, int nb) {
    __shared__ int s[512];
    int t = threadIdx.x;
    int v = (t < nb) ? blockSums[t] : 0;
    s[t] = v;
    __syncthreads();
    for (int d = 1; d < 512; d <<= 1) {
        int add = (t >= d) ? s[t - d] : 0;
        __syncthreads();
        s[t] += add;
        __syncthreads();
    }
    if (t < nb) blockOffs[t] = s[t] - v;
}

// apply block offsets; init cursor; degf -> dinv in place; row_ptr[N] = E
__global__ void finalize(int* __restrict__ row_ptr, const int* __restrict__ blockOffs,
                         int* __restrict__ cursor, float* __restrict__ degf, int N, int E) {
    int i = blockIdx.x * 256 + threadIdx.x;
    if (i < N) {
        int rp = row_ptr[i] + blockOffs[i >> 8];
        row_ptr[i] = rp;
        cursor[i] = rp;
        degf[i] = rsqrtf(degf[i] + 1.0f);   // +1 = self-loop; always > 0
    }
    if (i == 0) row_ptr[N] = E;
}

// bucket edges by dst; fold dinv[src]*w into the stored weight
__global__ void build_csr(const int* __restrict__ src, const int* __restrict__ dst,
                          const float* __restrict__ w, const float* __restrict__ dinv,
                          int* __restrict__ cursor, int* __restrict__ src_s,
                          float* __restrict__ nw_s, int E) {
    int e = blockIdx.x * 256 + threadIdx.x;
    if (e < E) {
        int d = dst[e];
        int s = src[e];
        int pos = atomicAdd(cursor + d, 1);
        src_s[pos] = s;
        nw_s[pos] = w[e] * dinv[s];
    }
}

// ---------------- dense GEMMs (vector ALU; no fp32 MFMA on CDNA4) ----------------
__global__ void gemm_64_64(const float* __restrict__ X, const float* __restrict__ W,
                           float* __restrict__ H, int N) {
    __shared__ float Ws[64 * 64];
    int tid = threadIdx.x;
    for (int i = tid; i < 64 * 64; i += 256) Ws[i] = W[i];
    __syncthreads();
    int row = blockIdx.x * 16 + (tid >> 4);
    if (row >= N) return;
    int cg = (tid & 15) << 2;
    const float4* xrow = (const float4*)(X + (long long)row * 64);
    float4 acc = make_float4(0.f, 0.f, 0.f, 0.f);
#pragma unroll
    for (int kk = 0; kk < 16; ++kk) {
        float4 xv = xrow[kk];
        float xs[4] = {xv.x, xv.y, xv.z, xv.w};
#pragma unroll
        for (int j = 0; j < 4; ++j) {
            const float* wr = Ws + (kk * 4 + j) * 64 + cg;
            acc.x += xs[j] * wr[0];
            acc.y += xs[j] * wr[1];
            acc.z += xs[j] * wr[2];
            acc.w += xs[j] * wr[3];
        }
    }
    ((float4*)(H + (long long)row * 64))[tid & 15] = acc;
}

__global__ void gemm_relu_64_32(const float* __restrict__ X, const float* __restrict__ W,
                                float* __restrict__ H, int N) {
    __shared__ float Ws[64 * 32];
    int tid = threadIdx.x;
    for (int i = tid; i < 64 * 32; i += 256) Ws[i] = W[i];
    __syncthreads();
    int row = blockIdx.x * 32 + (tid >> 3);
    if (row >= N) return;
    int cg = (tid & 7) << 2;
    const float4* xrow = (const float4*)(X + (long long)row * 64);
    float4 acc = make_float4(0.f, 0.f, 0.f, 0.f);
#pragma unroll
    for (int kk = 0; kk < 16; ++kk) {
        float4 xv = xrow[kk];
        float xs[4] = {fmaxf(xv.x, 0.f), fmaxf(xv.y, 0.f), fmaxf(xv.z, 0.f), fmaxf(xv.w, 0.f)};
#pragma unroll
        for (int j = 0; j < 4; ++j) {
            const float* wr = Ws + (kk * 4 + j) * 32 + cg;
            acc.x += xs[j] * wr[0];
            acc.y += xs[j] * wr[1];
            acc.z += xs[j] * wr[2];
            acc.w += xs[j] * wr[3];
        }
    }
    ((float4*)(H + (long long)row * 32))[tid & 7] = acc;
}

// ---------------- aggregation (CSR gather, no atomics) ----------------
// one wave per node, lane = channel (64 ch)
__global__ void aggregate64(const float* __restrict__ h, const int* __restrict__ row_ptr,
                            const int* __restrict__ src_s, const float* __restrict__ nw_s,
                            const float* __restrict__ dinv, const float* __restrict__ b,
                            float* __restrict__ out, int N) {
    int wv = threadIdx.x >> 6;
    int lane = threadIdx.x & 63;
    int i = blockIdx.x * 4 + wv;
    if (i >= N) return;
    int beg = row_ptr[i], end = row_ptr[i + 1];
    float acc = 0.f;
    for (int e = beg; e < end; ++e) {
        int s = src_s[e];                       // wave-uniform (broadcast)
        acc += nw_s[e] * h[(long long)s * 64 + lane];
    }
    float di = dinv[i];
    long long base = (long long)i * 64 + lane;
    out[base] = b[lane] + di * (di * h[base] + acc);
}

// one wave per node (32 ch): half-waves take alternating edges, combine via shfl
__global__ void aggregate32(const float* __restrict__ h, const int* __restrict__ row_ptr,
                            const int* __restrict__ src_s, const float* __restrict__ nw_s,
                            const float* __restrict__ dinv, const float* __restrict__ b,
                            float* __restrict__ out, int N) {
    int wv = threadIdx.x >> 6;
    int lane = threadIdx.x & 63;
    int half = lane >> 5;
    int ch = lane & 31;
    int i = blockIdx.x * 4 + wv;
    if (i >= N) return;
    int beg = row_ptr[i], end = row_ptr[i + 1];
    float acc = 0.f;
    for (int e = beg + half; e < end; e += 2) {
        int s = src_s[e];
        acc += nw_s[e] * h[(long long)s * 32 + ch];
    }
    acc += __shfl_xor(acc, 32, 64);             // combine the two half-wave partials
    if (half == 0) {
        float di = dinv[i];
        long long base = (long long)i * 32 + ch;
        out[base] = b[ch] + di * (di * h[base] + acc);
    }
}

extern "C" void kernel_launch(void* const* d_in, const int* in_sizes, int n_in,
                              void* d_out, int out_size, void* d_ws, size_t ws_size,
                              hipStream_t stream) {
    const float* x  = (const float*)d_in[0];
    const int* eidx = (const int*)d_in[1];      // int64 in reference -> int32 on device
    const float* w  = (const float*)d_in[2];
    const float* W1 = (const float*)d_in[3];
    const float* b1 = (const float*)d_in[4];
    const float* W2 = (const float*)d_in[5];
    const float* b2 = (const float*)d_in[6];
    float* out = (float*)d_out;

    const int E = in_sizes[2];
    const int N = in_sizes[0] / 64;
    const int* src = eidx;
    const int* dst = eidx + E;
    const int nb = ceil_div(N, 256);            // 391 for N=100000; must be <= 512

    // workspace carve-up (256B-aligned): ~62 MB
    char* ws = (char*)d_ws;
    size_t off = 0;
    auto alloc = [&](size_t bytes) -> void* {
        void* p = ws + off;
        off = (off + bytes + 255) & ~(size_t)255;
        return p;
    };
    int*   cnt       = (int*)alloc((size_t)N * 4);
    int*   row_ptr   = (int*)alloc((size_t)(N + 1) * 4);
    int*   cursor    = (int*)alloc((size_t)N * 4);
    int*   blockSums = (int*)alloc(512 * 4);
    int*   blockOffs = (int*)alloc(512 * 4);
    float* dinv      = (float*)alloc((size_t)N * 4);   // degf -> dinv in place
    int*   src_s     = (int*)alloc((size_t)E * 4);
    float* nw_s      = (float*)alloc((size_t)E * 4);
    float* bufA      = (float*)alloc((size_t)N * 64 * 4);
    float* bufB      = (float*)alloc((size_t)N * 64 * 4);

    // CSR build
    zero_counts<<<nb, 256, 0, stream>>>(cnt, dinv, N);
    histogram<<<ceil_div(E, 256), 256, 0, stream>>>(dst, w, cnt, dinv, E);
    scan1<<<nb, 256, 0, stream>>>(cnt, row_ptr, blockSums, N);
    scan2<<<1, 512, 0, stream>>>(blockSums, blockOffs, nb);
    finalize<<<nb, 256, 0, stream>>>(row_ptr, blockOffs, cursor, dinv, N, E);
    build_csr<<<ceil_div(E, 256), 256, 0, stream>>>(src, dst, w, dinv, cursor, src_s, nw_s, E);

    // layer 1
    gemm_64_64<<<ceil_div(N, 16), 256, 0, stream>>>(x, W1, bufA, N);
    aggregate64<<<ceil_div(N, 4), 256, 0, stream>>>(bufA, row_ptr, src_s, nw_s, dinv, b1, bufB, N);

    // layer 2
    gemm_relu_64_32<<<ceil_div(N, 32), 256, 0, stream>>>(bufB, W2, bufA, N);
    aggregate32<<<ceil_div(N, 4), 256, 0, stream>>>(bufA, row_ptr, src_s, nw_s, dinv, b2, out, N);
}

// Round 4
// 399.625 us; speedup vs baseline: 4.2754x; 1.2423x over previous
//
#include <hip/hip_runtime.h>

static inline int ceil_div(long long a, long long b) { return (int)((a + b - 1) / b); }

// ---------------- CSR build ----------------
__global__ void zero_counts(int* __restrict__ cnt, float* __restrict__ degf, int N) {
    int i = blockIdx.x * 256 + threadIdx.x;
    if (i < N) { cnt[i] = 0; degf[i] = 0.f; }
}

__global__ void histogram(const int* __restrict__ dst, const float* __restrict__ w,
                          int* __restrict__ cnt, float* __restrict__ degf, int E) {
    int e = blockIdx.x * 256 + threadIdx.x;
    if (e < E) {
        int d = dst[e];
        atomicAdd(cnt + d, 1);
        atomicAdd(degf + d, w[e]);
    }
}

// per-256-block inclusive scan -> exclusive results + block sums
__global__ void scan1(const int* __restrict__ cnt, int* __restrict__ excl,
                      int* __restrict__ blockSums, int N) {
    __shared__ int s[256];
    int t = threadIdx.x;
    int i = blockIdx.x * 256 + t;
    int v = (i < N) ? cnt[i] : 0;
    s[t] = v;
    __syncthreads();
    for (int d = 1; d < 256; d <<= 1) {
        int add = (t >= d) ? s[t - d] : 0;
        __syncthreads();
        s[t] += add;
        __syncthreads();
    }
    if (i < N) excl[i] = s[t] - v;
    if (t == 255) blockSums[blockIdx.x] = s[t];
}

// single-block scan of block sums (nb <= 512)
__global__ void scan2(const int* __restrict__ blockSums, int* __restrict__ blockOffs, int nb) {
    __shared__ int s[512];
    int t = threadIdx.x;
    int v = (t < nb) ? blockSums[t] : 0;
    s[t] = v;
    __syncthreads();
    for (int d = 1; d < 512; d <<= 1) {
        int add = (t >= d) ? s[t - d] : 0;
        __syncthreads();
        s[t] += add;
        __syncthreads();
    }
    if (t < nb) blockOffs[t] = s[t] - v;
}

// apply block offsets; init cursor; degf -> dinv in place; row_ptr[N] = E
__global__ void finalize(int* __restrict__ row_ptr, const int* __restrict__ blockOffs,
                         int* __restrict__ cursor, float* __restrict__ degf, int N, int E) {
    int i = blockIdx.x * 256 + threadIdx.x;
    if (i < N) {
        int rp = row_ptr[i] + blockOffs[i >> 8];
        row_ptr[i] = rp;
        cursor[i] = rp;
        degf[i] = rsqrtf(degf[i] + 1.0f);   // +1 = self-loop; always > 0
    }
    if (i == 0) row_ptr[N] = E;
}

// bucket edges by dst; fold dinv[src]*w into the stored weight
__global__ void build_csr(const int* __restrict__ src, const int* __restrict__ dst,
                          const float* __restrict__ w, const float* __restrict__ dinv,
                          int* __restrict__ cursor, int* __restrict__ src_s,
                          float* __restrict__ nw_s, int E) {
    int e = blockIdx.x * 256 + threadIdx.x;
    if (e < E) {
        int d = dst[e];
        int s = src[e];
        int pos = atomicAdd(cursor + d, 1);
        src_s[pos] = s;
        nw_s[pos] = w[e] * dinv[s];
    }
}

// ---------------- dense GEMMs (vector ALU; no fp32 MFMA on CDNA4) ----------------
__global__ void gemm_64_64(const float* __restrict__ X, const float* __restrict__ W,
                           float* __restrict__ H, int N) {
    __shared__ float Ws[64 * 64];
    int tid = threadIdx.x;
    for (int i = tid; i < 64 * 64; i += 256) Ws[i] = W[i];
    __syncthreads();
    int row = blockIdx.x * 16 + (tid >> 4);
    if (row >= N) return;
    int cg = (tid & 15) << 2;
    const float4* xrow = (const float4*)(X + (long long)row * 64);
    float4 acc = make_float4(0.f, 0.f, 0.f, 0.f);
#pragma unroll
    for (int kk = 0; kk < 16; ++kk) {
        float4 xv = xrow[kk];
        float xs[4] = {xv.x, xv.y, xv.z, xv.w};
#pragma unroll
        for (int j = 0; j < 4; ++j) {
            const float* wr = Ws + (kk * 4 + j) * 64 + cg;
            acc.x += xs[j] * wr[0];
            acc.y += xs[j] * wr[1];
            acc.z += xs[j] * wr[2];
            acc.w += xs[j] * wr[3];
        }
    }
    ((float4*)(H + (long long)row * 64))[tid & 15] = acc;
}

__global__ void gemm_relu_64_32(const float* __restrict__ X, const float* __restrict__ W,
                                float* __restrict__ H, int N) {
    __shared__ float Ws[64 * 32];
    int tid = threadIdx.x;
    for (int i = tid; i < 64 * 32; i += 256) Ws[i] = W[i];
    __syncthreads();
    int row = blockIdx.x * 32 + (tid >> 3);
    if (row >= N) return;
    int cg = (tid & 7) << 2;
    const float4* xrow = (const float4*)(X + (long long)row * 64);
    float4 acc = make_float4(0.f, 0.f, 0.f, 0.f);
#pragma unroll
    for (int kk = 0; kk < 16; ++kk) {
        float4 xv = xrow[kk];
        float xs[4] = {fmaxf(xv.x, 0.f), fmaxf(xv.y, 0.f), fmaxf(xv.z, 0.f), fmaxf(xv.w, 0.f)};
#pragma unroll
        for (int j = 0; j < 4; ++j) {
            const float* wr = Ws + (kk * 4 + j) * 32 + cg;
            acc.x += xs[j] * wr[0];
            acc.y += xs[j] * wr[1];
            acc.z += xs[j] * wr[2];
            acc.w += xs[j] * wr[3];
        }
    }
    ((float4*)(H + (long long)row * 32))[tid & 7] = acc;
}

// ---------------- aggregation (CSR gather, no atomics, edge-level ILP) ----------------
// one wave per node, 64 ch: 4 quarters x 16 lanes, lane reads float4.
// Each quarter takes every 4th edge; 2x unroll -> up to 8 gathers in flight per wave.
__global__ void aggregate64(const float* __restrict__ h, const int* __restrict__ row_ptr,
                            const int* __restrict__ src_s, const float* __restrict__ nw_s,
                            const float* __restrict__ dinv, const float* __restrict__ b,
                            float* __restrict__ out, int N) {
    int wv = threadIdx.x >> 6;        // wave in block (8 waves / 512 threads)
    int lane = threadIdx.x & 63;
    int q = lane >> 4;                // quarter 0..3
    int c = lane & 15;                // float4 channel group (16 x 4 = 64 ch)
    int i = blockIdx.x * 8 + wv;
    if (i >= N) return;
    int beg = row_ptr[i], end = row_ptr[i + 1];
    const float4* h4 = (const float4*)h;
    float4 acc = make_float4(0.f, 0.f, 0.f, 0.f);
    int e = beg + q;
    for (; e + 4 < end; e += 8) {
        int s0 = src_s[e];
        int s1 = src_s[e + 4];
        float w0 = nw_s[e];
        float w1 = nw_s[e + 4];
        float4 h0 = h4[(long long)s0 * 16 + c];
        float4 h1 = h4[(long long)s1 * 16 + c];
        acc.x += w0 * h0.x + w1 * h1.x;
        acc.y += w0 * h0.y + w1 * h1.y;
        acc.z += w0 * h0.z + w1 * h1.z;
        acc.w += w0 * h0.w + w1 * h1.w;
    }
    if (e < end) {
        int s0 = src_s[e];
        float w0 = nw_s[e];
        float4 h0 = h4[(long long)s0 * 16 + c];
        acc.x += w0 * h0.x;
        acc.y += w0 * h0.y;
        acc.z += w0 * h0.z;
        acc.w += w0 * h0.w;
    }
    // cross-quarter reduction: lanes l, l+16, l+32, l+48 hold partials for the same channels
    acc.x += __shfl_xor(acc.x, 16, 64);
    acc.y += __shfl_xor(acc.y, 16, 64);
    acc.z += __shfl_xor(acc.z, 16, 64);
    acc.w += __shfl_xor(acc.w, 16, 64);
    acc.x += __shfl_xor(acc.x, 32, 64);
    acc.y += __shfl_xor(acc.y, 32, 64);
    acc.z += __shfl_xor(acc.z, 32, 64);
    acc.w += __shfl_xor(acc.w, 32, 64);
    if (q == 0) {
        float di = dinv[i];
        float4 hv = h4[(long long)i * 16 + c];
        float4 bv = ((const float4*)b)[c];
        float4 o;
        o.x = bv.x + di * (di * hv.x + acc.x);
        o.y = bv.y + di * (di * hv.y + acc.y);
        o.z = bv.z + di * (di * hv.z + acc.z);
        o.w = bv.w + di * (di * hv.w + acc.w);
        ((float4*)out)[(long long)i * 16 + c] = o;
    }
}

// one wave per node, 32 ch: 8 slices x 8 lanes, lane reads float4.
// Each slice takes every 8th edge; 2x unroll -> up to 16 gathers in flight.
__global__ void aggregate32(const float* __restrict__ h, const int* __restrict__ row_ptr,
                            const int* __restrict__ src_s, const float* __restrict__ nw_s,
                            const float* __restrict__ dinv, const float* __restrict__ b,
                            float* __restrict__ out, int N) {
    int wv = threadIdx.x >> 6;
    int lane = threadIdx.x & 63;
    int sl = lane >> 3;               // slice 0..7
    int c = lane & 7;                 // float4 channel group (8 x 4 = 32 ch)
    int i = blockIdx.x * 8 + wv;
    if (i >= N) return;
    int beg = row_ptr[i], end = row_ptr[i + 1];
    const float4* h4 = (const float4*)h;
    float4 acc = make_float4(0.f, 0.f, 0.f, 0.f);
    int e = beg + sl;
    for (; e + 8 < end; e += 16) {
        int s0 = src_s[e];
        int s1 = src_s[e + 8];
        float w0 = nw_s[e];
        float w1 = nw_s[e + 8];
        float4 h0 = h4[(long long)s0 * 8 + c];
        float4 h1 = h4[(long long)s1 * 8 + c];
        acc.x += w0 * h0.x + w1 * h1.x;
        acc.y += w0 * h0.y + w1 * h1.y;
        acc.z += w0 * h0.z + w1 * h1.z;
        acc.w += w0 * h0.w + w1 * h1.w;
    }
    if (e < end) {
        int s0 = src_s[e];
        float w0 = nw_s[e];
        float4 h0 = h4[(long long)s0 * 8 + c];
        acc.x += w0 * h0.x;
        acc.y += w0 * h0.y;
        acc.z += w0 * h0.z;
        acc.w += w0 * h0.w;
    }
    // cross-slice reduction (slices at lane strides 8, 16, 32)
    acc.x += __shfl_xor(acc.x, 8, 64);
    acc.y += __shfl_xor(acc.y, 8, 64);
    acc.z += __shfl_xor(acc.z, 8, 64);
    acc.w += __shfl_xor(acc.w, 8, 64);
    acc.x += __shfl_xor(acc.x, 16, 64);
    acc.y += __shfl_xor(acc.y, 16, 64);
    acc.z += __shfl_xor(acc.z, 16, 64);
    acc.w += __shfl_xor(acc.w, 16, 64);
    acc.x += __shfl_xor(acc.x, 32, 64);
    acc.y += __shfl_xor(acc.y, 32, 64);
    acc.z += __shfl_xor(acc.z, 32, 64);
    acc.w += __shfl_xor(acc.w, 32, 64);
    if (sl == 0) {
        float di = dinv[i];
        float4 hv = h4[(long long)i * 8 + c];
        float4 bv = ((const float4*)b)[c];
        float4 o;
        o.x = bv.x + di * (di * hv.x + acc.x);
        o.y = bv.y + di * (di * hv.y + acc.y);
        o.z = bv.z + di * (di * hv.z + acc.z);
        o.w = bv.w + di * (di * hv.w + acc.w);
        ((float4*)out)[(long long)i * 8 + c] = o;
    }
}

extern "C" void kernel_launch(void* const* d_in, const int* in_sizes, int n_in,
                              void* d_out, int out_size, void* d_ws, size_t ws_size,
                              hipStream_t stream) {
    const float* x  = (const float*)d_in[0];
    const int* eidx = (const int*)d_in[1];      // int64 in reference -> int32 on device
    const float* w  = (const float*)d_in[2];
    const float* W1 = (const float*)d_in[3];
    const float* b1 = (const float*)d_in[4];
    const float* W2 = (const float*)d_in[5];
    const float* b2 = (const float*)d_in[6];
    float* out = (float*)d_out;

    const int E = in_sizes[2];
    const int N = in_sizes[0] / 64;
    const int* src = eidx;
    const int* dst = eidx + E;
    const int nb = ceil_div(N, 256);            // 391 for N=100000; must be <= 512

    // workspace carve-up (256B-aligned): ~62 MB
    char* ws = (char*)d_ws;
    size_t off = 0;
    auto alloc = [&](size_t bytes) -> void* {
        void* p = ws + off;
        off = (off + bytes + 255) & ~(size_t)255;
        return p;
    };
    int*   cnt       = (int*)alloc((size_t)N * 4);
    int*   row_ptr   = (int*)alloc((size_t)(N + 1) * 4);
    int*   cursor    = (int*)alloc((size_t)N * 4);
    int*   blockSums = (int*)alloc(512 * 4);
    int*   blockOffs = (int*)alloc(512 * 4);
    float* dinv      = (float*)alloc((size_t)N * 4);   // degf -> dinv in place
    int*   src_s     = (int*)alloc((size_t)E * 4);
    float* nw_s      = (float*)alloc((size_t)E * 4);
    float* bufA      = (float*)alloc((size_t)N * 64 * 4);
    float* bufB      = (float*)alloc((size_t)N * 64 * 4);

    // CSR build
    zero_counts<<<nb, 256, 0, stream>>>(cnt, dinv, N);
    histogram<<<ceil_div(E, 256), 256, 0, stream>>>(dst, w, cnt, dinv, E);
    scan1<<<nb, 256, 0, stream>>>(cnt, row_ptr, blockSums, N);
    scan2<<<1, 512, 0, stream>>>(blockSums, blockOffs, nb);
    finalize<<<nb, 256, 0, stream>>>(row_ptr, blockOffs, cursor, dinv, N, E);
    build_csr<<<ceil_div(E, 256), 256, 0, stream>>>(src, dst, w, dinv, cursor, src_s, nw_s, E);

    // layer 1
    gemm_64_64<<<ceil_div(N, 16), 256, 0, stream>>>(x, W1, bufA, N);
    aggregate64<<<ceil_div(N, 8), 512, 0, stream>>>(bufA, row_ptr, src_s, nw_s, dinv, b1, bufB, N);

    // layer 2
    gemm_relu_64_32<<<ceil_div(N, 32), 256, 0, stream>>>(bufB, W2, bufA, N);
    aggregate32<<<ceil_div(N, 8), 512, 0, stream>>>(bufA, row_ptr, src_s, nw_s, dinv, b2, out, N);
}

// Round 5
// 318.360 us; speedup vs baseline: 5.3667x; 1.2553x over previous
//
#include <hip/hip_runtime.h>

static inline int ceil_div(long long a, long long b) { return (int)((a + b - 1) / b); }

#define QSCALE 32767.0f
#define QINV   (1.0f / 32767.0f)

// ---------------- build: one-pass bucket scatter ----------------
__global__ void zero2(int* __restrict__ cnt, float* __restrict__ degf, int N) {
    int i = blockIdx.x * 256 + threadIdx.x;
    if (i < N) { cnt[i] = 0; degf[i] = 0.f; }
}

// entry = (src << 15) | round-down(w * 32767); src < 2^17, w in [0,1)
__global__ void bucket_scatter(const int* __restrict__ src, const int* __restrict__ dst,
                               const float* __restrict__ w, int* __restrict__ cnt,
                               unsigned* __restrict__ bucket, int CAP, int E) {
    int e = blockIdx.x * 256 + threadIdx.x;
    if (e < E) {
        int d = dst[e];
        int slot = atomicAdd(cnt + d, 1);
        if (slot < CAP) {
            unsigned v = ((unsigned)src[e] << 15) | (unsigned)(w[e] * QSCALE);
            bucket[(size_t)d * CAP + slot] = v;
        }
    }
}

// overflow nodes (cnt > CAP): accumulate true weighted degree via atomics
__global__ void degfix(const int* __restrict__ dst, const float* __restrict__ w,
                       const int* __restrict__ cnt, float* __restrict__ degf,
                       int CAP, int E) {
    int e = blockIdx.x * 256 + threadIdx.x;
    if (e < E) {
        int d = dst[e];
        if (cnt[d] > CAP) atomicAdd(degf + d, w[e]);
    }
}

// per node: deg = bucket sum (or degf if overflowed); dinv = rsqrt(deg + 1)
__global__ void prep_dinv(const unsigned* __restrict__ bucket, const int* __restrict__ cnt,
                          const float* __restrict__ degf, float* __restrict__ dinv,
                          int CAP, int N) {
    int i = blockIdx.x * 256 + threadIdx.x;
    if (i >= N) return;
    int c = cnt[i];
    float deg;
    if (c <= CAP) {
        const unsigned* row = bucket + (size_t)i * CAP;
        deg = 0.f;
        for (int j = 0; j < c; ++j) deg += (float)(row[j] & 32767u) * QINV;
    } else {
        deg = degf[i];
    }
    dinv[i] = rsqrtf(deg + 1.0f);   // +1 = self-loop weight; always > 0
}

// ---------------- dense GEMMs (vector ALU; no fp32 MFMA on CDNA4) ----------------
__global__ void gemm_64_64(const float* __restrict__ X, const float* __restrict__ W,
                           float* __restrict__ H, int N) {
    __shared__ float Ws[64 * 64];
    int tid = threadIdx.x;
    for (int i = tid; i < 64 * 64; i += 256) Ws[i] = W[i];
    __syncthreads();
    int row = blockIdx.x * 16 + (tid >> 4);
    if (row >= N) return;
    int cg = (tid & 15) << 2;
    const float4* xrow = (const float4*)(X + (long long)row * 64);
    float4 acc = make_float4(0.f, 0.f, 0.f, 0.f);
#pragma unroll
    for (int kk = 0; kk < 16; ++kk) {
        float4 xv = xrow[kk];
        float xs[4] = {xv.x, xv.y, xv.z, xv.w};
#pragma unroll
        for (int j = 0; j < 4; ++j) {
            const float* wr = Ws + (kk * 4 + j) * 64 + cg;
            acc.x += xs[j] * wr[0];
            acc.y += xs[j] * wr[1];
            acc.z += xs[j] * wr[2];
            acc.w += xs[j] * wr[3];
        }
    }
    ((float4*)(H + (long long)row * 64))[tid & 15] = acc;
}

__global__ void gemm_relu_64_32(const float* __restrict__ X, const float* __restrict__ W,
                                float* __restrict__ H, int N) {
    __shared__ float Ws[64 * 32];
    int tid = threadIdx.x;
    for (int i = tid; i < 64 * 32; i += 256) Ws[i] = W[i];
    __syncthreads();
    int row = blockIdx.x * 32 + (tid >> 3);
    if (row >= N) return;
    int cg = (tid & 7) << 2;
    const float4* xrow = (const float4*)(X + (long long)row * 64);
    float4 acc = make_float4(0.f, 0.f, 0.f, 0.f);
#pragma unroll
    for (int kk = 0; kk < 16; ++kk) {
        float4 xv = xrow[kk];
        float xs[4] = {fmaxf(xv.x, 0.f), fmaxf(xv.y, 0.f), fmaxf(xv.z, 0.f), fmaxf(xv.w, 0.f)};
#pragma unroll
        for (int j = 0; j < 4; ++j) {
            const float* wr = Ws + (kk * 4 + j) * 32 + cg;
            acc.x += xs[j] * wr[0];
            acc.y += xs[j] * wr[1];
            acc.z += xs[j] * wr[2];
            acc.w += xs[j] * wr[3];
        }
    }
    ((float4*)(H + (long long)row * 32))[tid & 7] = acc;
}

// ---------------- aggregation (bucket gather, edge-level ILP) ----------------
// one wave per node, 64 ch: 4 quarters x 16 lanes, lane reads float4 of h-row.
__global__ void aggregate64(const float* __restrict__ h, const unsigned* __restrict__ bucket,
                            const int* __restrict__ cnt, const float* __restrict__ dinv,
                            const float* __restrict__ b, float* __restrict__ out,
                            int CAP, int N) {
    int wv = threadIdx.x >> 6;
    int lane = threadIdx.x & 63;
    int q = lane >> 4;                // quarter 0..3
    int c = lane & 15;                // float4 channel group
    int i = blockIdx.x * 8 + wv;
    if (i >= N) return;
    int c_all = cnt[i];
    int m = (c_all <= CAP) ? c_all : 0;   // overflow node -> self term only; aggfix adds edges
    const unsigned* row = bucket + (size_t)i * CAP;
    const float4* h4 = (const float4*)h;
    float4 acc = make_float4(0.f, 0.f, 0.f, 0.f);
    int e = q;
    for (; e + 4 < m; e += 8) {
        unsigned v0 = row[e];
        unsigned v1 = row[e + 4];
        int s0 = v0 >> 15;
        int s1 = v1 >> 15;
        float n0 = (float)(v0 & 32767u) * QINV * dinv[s0];
        float n1 = (float)(v1 & 32767u) * QINV * dinv[s1];
        float4 h0 = h4[(size_t)s0 * 16 + c];
        float4 h1 = h4[(size_t)s1 * 16 + c];
        acc.x += n0 * h0.x + n1 * h1.x;
        acc.y += n0 * h0.y + n1 * h1.y;
        acc.z += n0 * h0.z + n1 * h1.z;
        acc.w += n0 * h0.w + n1 * h1.w;
    }
    if (e < m) {
        unsigned v0 = row[e];
        int s0 = v0 >> 15;
        float n0 = (float)(v0 & 32767u) * QINV * dinv[s0];
        float4 h0 = h4[(size_t)s0 * 16 + c];
        acc.x += n0 * h0.x;
        acc.y += n0 * h0.y;
        acc.z += n0 * h0.z;
        acc.w += n0 * h0.w;
    }
    acc.x += __shfl_xor(acc.x, 16, 64);
    acc.y += __shfl_xor(acc.y, 16, 64);
    acc.z += __shfl_xor(acc.z, 16, 64);
    acc.w += __shfl_xor(acc.w, 16, 64);
    acc.x += __shfl_xor(acc.x, 32, 64);
    acc.y += __shfl_xor(acc.y, 32, 64);
    acc.z += __shfl_xor(acc.z, 32, 64);
    acc.w += __shfl_xor(acc.w, 32, 64);
    if (q == 0) {
        float di = dinv[i];
        float4 hv = h4[(size_t)i * 16 + c];
        float4 bv = ((const float4*)b)[c];
        float4 o;
        o.x = bv.x + di * (di * hv.x + acc.x);
        o.y = bv.y + di * (di * hv.y + acc.y);
        o.z = bv.z + di * (di * hv.z + acc.z);
        o.w = bv.w + di * (di * hv.w + acc.w);
        ((float4*)out)[(size_t)i * 16 + c] = o;
    }
}

// one wave per node, 32 ch: 8 slices x 8 lanes
__global__ void aggregate32(const float* __restrict__ h, const unsigned* __restrict__ bucket,
                            const int* __restrict__ cnt, const float* __restrict__ dinv,
                            const float* __restrict__ b, float* __restrict__ out,
                            int CAP, int N) {
    int wv = threadIdx.x >> 6;
    int lane = threadIdx.x & 63;
    int sl = lane >> 3;               // slice 0..7
    int c = lane & 7;                 // float4 channel group
    int i = blockIdx.x * 8 + wv;
    if (i >= N) return;
    int c_all = cnt[i];
    int m = (c_all <= CAP) ? c_all : 0;
    const unsigned* row = bucket + (size_t)i * CAP;
    const float4* h4 = (const float4*)h;
    float4 acc = make_float4(0.f, 0.f, 0.f, 0.f);
    int e = sl;
    for (; e + 8 < m; e += 16) {
        unsigned v0 = row[e];
        unsigned v1 = row[e + 8];
        int s0 = v0 >> 15;
        int s1 = v1 >> 15;
        float n0 = (float)(v0 & 32767u) * QINV * dinv[s0];
        float n1 = (float)(v1 & 32767u) * QINV * dinv[s1];
        float4 h0 = h4[(size_t)s0 * 8 + c];
        float4 h1 = h4[(size_t)s1 * 8 + c];
        acc.x += n0 * h0.x + n1 * h1.x;
        acc.y += n0 * h0.y + n1 * h1.y;
        acc.z += n0 * h0.z + n1 * h1.z;
        acc.w += n0 * h0.w + n1 * h1.w;
    }
    if (e < m) {
        unsigned v0 = row[e];
        int s0 = v0 >> 15;
        float n0 = (float)(v0 & 32767u) * QINV * dinv[s0];
        float4 h0 = h4[(size_t)s0 * 8 + c];
        acc.x += n0 * h0.x;
        acc.y += n0 * h0.y;
        acc.z += n0 * h0.z;
        acc.w += n0 * h0.w;
    }
    acc.x += __shfl_xor(acc.x, 8, 64);
    acc.y += __shfl_xor(acc.y, 8, 64);
    acc.z += __shfl_xor(acc.z, 8, 64);
    acc.w += __shfl_xor(acc.w, 8, 64);
    acc.x += __shfl_xor(acc.x, 16, 64);
    acc.y += __shfl_xor(acc.y, 16, 64);
    acc.z += __shfl_xor(acc.z, 16, 64);
    acc.w += __shfl_xor(acc.w, 16, 64);
    acc.x += __shfl_xor(acc.x, 32, 64);
    acc.y += __shfl_xor(acc.y, 32, 64);
    acc.z += __shfl_xor(acc.z, 32, 64);
    acc.w += __shfl_xor(acc.w, 32, 64);
    if (sl == 0) {
        float di = dinv[i];
        float4 hv = h4[(size_t)i * 8 + c];
        float4 bv = ((const float4*)b)[c];
        float4 o;
        o.x = bv.x + di * (di * hv.x + acc.x);
        o.y = bv.y + di * (di * hv.y + acc.y);
        o.z = bv.z + di * (di * hv.z + acc.z);
        o.w = bv.w + di * (di * hv.w + acc.w);
        ((float4*)out)[(size_t)i * 8 + c] = o;
    }
}

// slow-path: edges of overflowed nodes (cnt > CAP) via atomics; empty in practice
template <int C>
__global__ void aggfix(const int* __restrict__ src, const int* __restrict__ dst,
                       const float* __restrict__ w, const int* __restrict__ cnt,
                       const float* __restrict__ dinv, const float* __restrict__ h,
                       float* __restrict__ out, int CAP, int E) {
    int e = blockIdx.x * 256 + threadIdx.x;
    if (e >= E) return;
    int d = dst[e];
    if (cnt[d] <= CAP) return;
    int s = src[e];
    float nm = dinv[s] * w[e] * dinv[d];
    for (int ch = 0; ch < C; ++ch)
        atomicAdd(out + (size_t)d * C + ch, nm * h[(size_t)s * C + ch]);
}

extern "C" void kernel_launch(void* const* d_in, const int* in_sizes, int n_in,
                              void* d_out, int out_size, void* d_ws, size_t ws_size,
                              hipStream_t stream) {
    const float* x  = (const float*)d_in[0];
    const int* eidx = (const int*)d_in[1];      // int64 in reference -> int32 on device
    const float* w  = (const float*)d_in[2];
    const float* W1 = (const float*)d_in[3];
    const float* b1 = (const float*)d_in[4];
    const float* W2 = (const float*)d_in[5];
    const float* b2 = (const float*)d_in[6];
    float* out = (float*)d_out;

    const int E = in_sizes[2];
    const int N = in_sizes[0] / 64;
    const int* src = eidx;
    const int* dst = eidx + E;

    // workspace carve-up (256B-aligned)
    char* ws = (char*)d_ws;
    size_t off = 0;
    auto alloc = [&](size_t bytes) -> void* {
        void* p = ws + off;
        off = (off + bytes + 255) & ~(size_t)255;
        return p;
    };
    int*   cnt  = (int*)alloc((size_t)N * 4);
    float* degf = (float*)alloc((size_t)N * 4);
    float* dinv = (float*)alloc((size_t)N * 4);
    float* bufA = (float*)alloc((size_t)N * 64 * 4);   // h1, then h2
    float* bufB = (float*)alloc((size_t)N * 64 * 4);   // out1
    // remaining ws -> bucket; CAP adapts to whatever is available (overflow path keeps
    // correctness for ANY CAP; CAP >= ~40 makes overflow statistically empty)
    size_t avail = (ws_size > off) ? ws_size - off : 0;
    int CAP = (int)(avail / ((size_t)N * 4));
    if (CAP > 64) CAP = 64;
    unsigned* bucket = (unsigned*)(ws + off);

    const int nbN = ceil_div(N, 256);
    const int nbE = ceil_div(E, 256);

    // build
    zero2<<<nbN, 256, 0, stream>>>(cnt, degf, N);
    bucket_scatter<<<nbE, 256, 0, stream>>>(src, dst, w, cnt, bucket, CAP, E);
    degfix<<<nbE, 256, 0, stream>>>(dst, w, cnt, degf, CAP, E);
    prep_dinv<<<nbN, 256, 0, stream>>>(bucket, cnt, degf, dinv, CAP, N);

    // layer 1
    gemm_64_64<<<ceil_div(N, 16), 256, 0, stream>>>(x, W1, bufA, N);
    aggregate64<<<ceil_div(N, 8), 512, 0, stream>>>(bufA, bucket, cnt, dinv, b1, bufB, CAP, N);
    aggfix<64><<<nbE, 256, 0, stream>>>(src, dst, w, cnt, dinv, bufA, bufB, CAP, E);

    // layer 2
    gemm_relu_64_32<<<ceil_div(N, 32), 256, 0, stream>>>(bufB, W2, bufA, N);
    aggregate32<<<ceil_div(N, 8), 512, 0, stream>>>(bufA, bucket, cnt, dinv, b2, out, CAP, N);
    aggfix<32><<<nbE, 256, 0, stream>>>(src, dst, w, cnt, dinv, bufA, out, CAP, E);
}

// Round 6
// 272.820 us; speedup vs baseline: 6.2626x; 1.1669x over previous
//
#include <hip/hip_runtime.h>

static inline int ceil_div(long long a, long long b) { return (int)((a + b - 1) / b); }

// Node-range binning: bin = dst >> 8 (256 nodes per bin).
// Assumes N <= 131072 (src fits 17 bits when packed with 8-bit offset). N=100000 here.
#define RBITS 8
#define RNODES 256

// ---------------- build step 0: zero bin counters ----------------
__global__ void zero_bins(int* __restrict__ bin_sizes, int* __restrict__ bin_cursor, int NB) {
    int t = threadIdx.x;
    for (int i = t; i < NB; i += 512) { bin_sizes[i] = 0; bin_cursor[i] = 0; }
}

// ---------------- step 1: per-bin edge counts (LDS histogram) ----------------
__global__ void bin_count(const int* __restrict__ dst, int* __restrict__ bin_sizes,
                          int NB, int E) {
    __shared__ int hist[512];
    int t = threadIdx.x;
    hist[t] = 0;
    __syncthreads();
    for (int e = blockIdx.x * 512 + t; e < E; e += gridDim.x * 512)
        atomicAdd(&hist[dst[e] >> RBITS], 1);
    __syncthreads();
    if (t < NB && hist[t]) atomicAdd(&bin_sizes[t], hist[t]);
}

// ---------------- step 2: exclusive scan of bin sizes (one block) ----------------
__global__ void bin_scan(const int* __restrict__ bin_sizes, int* __restrict__ bin_start, int NB) {
    __shared__ int s[512];
    int t = threadIdx.x;
    int v = (t < NB) ? bin_sizes[t] : 0;
    s[t] = v;
    __syncthreads();
    for (int d = 1; d < 512; d <<= 1) {
        int a = (t >= d) ? s[t - d] : 0;
        __syncthreads();
        s[t] += a;
        __syncthreads();
    }
    if (t < NB) bin_start[t] = s[t] - v;       // exclusive
    if (t == NB - 1) bin_start[NB] = s[t];     // total = E
}

// ---------------- step 3: partition edges into bins (LDS staging) ----------------
#define SC_T 512
#define SC_K 8
#define SC_E (SC_T * SC_K)   // 4096 edges per block
__global__ void bin_scatter(const int* __restrict__ src, const int* __restrict__ dst,
                            const float* __restrict__ w, int* __restrict__ bin_cursor,
                            const int* __restrict__ bin_start,
                            int* __restrict__ bp, float* __restrict__ bw,
                            int NB, int E) {
    __shared__ int hist[512];
    __shared__ int offs[512];     // inclusive scan of hist
    __shared__ int base[512];     // global write base per bin
    __shared__ int stage_p[SC_E];
    __shared__ float stage_w[SC_E];
    int t = threadIdx.x;
    hist[t] = 0;
    __syncthreads();
    int e0 = blockIdx.x * SC_E;
    int nE = E - e0; if (nE > SC_E) nE = SC_E;

    int myBin[SC_K], myRank[SC_K], myPack[SC_K];
    float myW[SC_K];
#pragma unroll
    for (int k = 0; k < SC_K; ++k) {
        int idx = t + k * SC_T;
        if (idx < nE) {
            int e = e0 + idx;
            int d = dst[e];
            int b = d >> RBITS;
            myBin[k] = b;
            myPack[k] = (src[e] << RBITS) | (d & (RNODES - 1));
            myW[k] = w[e];
            myRank[k] = atomicAdd(&hist[b], 1);
        }
    }
    __syncthreads();
    // inclusive scan of hist into offs
    offs[t] = hist[t];
    __syncthreads();
    for (int d = 1; d < 512; d <<= 1) {
        int a = (t >= d) ? offs[t - d] : 0;
        __syncthreads();
        offs[t] += a;
        __syncthreads();
    }
    // reserve global runs
    if (t < NB && hist[t]) base[t] = bin_start[t] + atomicAdd(&bin_cursor[t], hist[t]);
    // stage grouped by bin
#pragma unroll
    for (int k = 0; k < SC_K; ++k) {
        int idx = t + k * SC_T;
        if (idx < nE) {
            int b = myBin[k];
            int pos = (offs[b] - hist[b]) + myRank[k];
            stage_p[pos] = myPack[k];
            stage_w[pos] = myW[k];
        }
    }
    __syncthreads();
    // coalesced-ish copy out (runs of same bin are contiguous)
    for (int p = t; p < nE; p += SC_T) {
        int lo = 0, hi = NB - 1;          // smallest b with offs[b] > p
        while (lo < hi) { int mid = (lo + hi) >> 1; if (offs[mid] > p) hi = mid; else lo = mid + 1; }
        int b = lo;
        int g = base[b] + (p - (offs[b] - hist[b]));
        bp[g] = stage_p[p];
        bw[g] = stage_w[p];
    }
}

// ---------------- step 4: per-bin counting sort -> dense CSR + dinv ----------------
__global__ void csr_build(const int* __restrict__ bp, const float* __restrict__ bw,
                          const int* __restrict__ bin_start,
                          int* __restrict__ row_beg, int* __restrict__ row_cnt,
                          float* __restrict__ dinv,
                          int* __restrict__ fsrc, float* __restrict__ fw,
                          int N, int NB) {
    __shared__ int cnt[RNODES];
    __shared__ float wsum[RNODES];
    __shared__ int starts[RNODES];
    __shared__ int cur[RNODES];
    int b = blockIdx.x;
    int t = threadIdx.x;   // 512
    if (t < RNODES) { cnt[t] = 0; wsum[t] = 0.f; }
    __syncthreads();
    int beg = bin_start[b], end = bin_start[b + 1];
    for (int e = beg + t; e < end; e += 512) {
        int off = bp[e] & (RNODES - 1);
        atomicAdd(&cnt[off], 1);
        atomicAdd(&wsum[off], bw[e]);
    }
    __syncthreads();
    if (t < RNODES) starts[t] = cnt[t];
    __syncthreads();
    for (int d = 1; d < RNODES; d <<= 1) {
        int a = 0;
        if (t < RNODES && t >= d) a = starts[t - d];
        __syncthreads();
        if (t < RNODES) starts[t] += a;
        __syncthreads();
    }
    if (t < RNODES) {
        int ex = starts[t] - cnt[t];
        cur[t] = beg + ex;
        int node = (b << RBITS) + t;
        if (node < N) {
            row_beg[node] = beg + ex;
            row_cnt[node] = cnt[t];
            dinv[node] = rsqrtf(wsum[t] + 1.0f);   // +1 = self-loop weight
        }
    }
    __syncthreads();
    for (int e = beg + t; e < end; e += 512) {
        int p = bp[e];
        int slot = atomicAdd(&cur[p & (RNODES - 1)], 1);
        fsrc[slot] = p >> RBITS;
        fw[slot] = bw[e];
    }
}

// ---------------- dense GEMMs (vector ALU; no fp32 MFMA on CDNA4) ----------------
__global__ void gemm_64_64(const float* __restrict__ X, const float* __restrict__ W,
                           float* __restrict__ H, int N) {
    __shared__ float Ws[64 * 64];
    int tid = threadIdx.x;
    for (int i = tid; i < 64 * 64; i += 256) Ws[i] = W[i];
    __syncthreads();
    int row = blockIdx.x * 16 + (tid >> 4);
    if (row >= N) return;
    int cg = (tid & 15) << 2;
    const float4* xrow = (const float4*)(X + (long long)row * 64);
    float4 acc = make_float4(0.f, 0.f, 0.f, 0.f);
#pragma unroll
    for (int kk = 0; kk < 16; ++kk) {
        float4 xv = xrow[kk];
        float xs[4] = {xv.x, xv.y, xv.z, xv.w};
#pragma unroll
        for (int j = 0; j < 4; ++j) {
            const float* wr = Ws + (kk * 4 + j) * 64 + cg;
            acc.x += xs[j] * wr[0];
            acc.y += xs[j] * wr[1];
            acc.z += xs[j] * wr[2];
            acc.w += xs[j] * wr[3];
        }
    }
    ((float4*)(H + (long long)row * 64))[tid & 15] = acc;
}

__global__ void gemm_relu_64_32(const float* __restrict__ X, const float* __restrict__ W,
                                float* __restrict__ H, int N) {
    __shared__ float Ws[64 * 32];
    int tid = threadIdx.x;
    for (int i = tid; i < 64 * 32; i += 256) Ws[i] = W[i];
    __syncthreads();
    int row = blockIdx.x * 32 + (tid >> 3);
    if (row >= N) return;
    int cg = (tid & 7) << 2;
    const float4* xrow = (const float4*)(X + (long long)row * 64);
    float4 acc = make_float4(0.f, 0.f, 0.f, 0.f);
#pragma unroll
    for (int kk = 0; kk < 16; ++kk) {
        float4 xv = xrow[kk];
        float xs[4] = {fmaxf(xv.x, 0.f), fmaxf(xv.y, 0.f), fmaxf(xv.z, 0.f), fmaxf(xv.w, 0.f)};
#pragma unroll
        for (int j = 0; j < 4; ++j) {
            const float* wr = Ws + (kk * 4 + j) * 32 + cg;
            acc.x += xs[j] * wr[0];
            acc.y += xs[j] * wr[1];
            acc.z += xs[j] * wr[2];
            acc.w += xs[j] * wr[3];
        }
    }
    ((float4*)(H + (long long)row * 32))[tid & 7] = acc;
}

// ---------------- aggregation (dense CSR gather, edge-level ILP) ----------------
// one wave per node, 64 ch: 4 quarters x 16 lanes, lane reads float4 of h-row.
__global__ void aggregate64(const float* __restrict__ h, const int* __restrict__ row_beg,
                            const int* __restrict__ row_cnt, const int* __restrict__ fsrc,
                            const float* __restrict__ fw, const float* __restrict__ dinv,
                            const float* __restrict__ b, float* __restrict__ out, int N) {
    int wv = threadIdx.x >> 6;
    int lane = threadIdx.x & 63;
    int q = lane >> 4;
    int c = lane & 15;
    int i = blockIdx.x * 8 + wv;
    if (i >= N) return;
    int beg = row_beg[i];
    int end = beg + row_cnt[i];
    const float4* h4 = (const float4*)h;
    float4 acc = make_float4(0.f, 0.f, 0.f, 0.f);
    int e = beg + q;
    for (; e + 4 < end; e += 8) {
        int s0 = fsrc[e];
        int s1 = fsrc[e + 4];
        float n0 = fw[e] * dinv[s0];
        float n1 = fw[e + 4] * dinv[s1];
        float4 h0 = h4[(size_t)s0 * 16 + c];
        float4 h1 = h4[(size_t)s1 * 16 + c];
        acc.x += n0 * h0.x + n1 * h1.x;
        acc.y += n0 * h0.y + n1 * h1.y;
        acc.z += n0 * h0.z + n1 * h1.z;
        acc.w += n0 * h0.w + n1 * h1.w;
    }
    if (e < end) {
        int s0 = fsrc[e];
        float n0 = fw[e] * dinv[s0];
        float4 h0 = h4[(size_t)s0 * 16 + c];
        acc.x += n0 * h0.x;
        acc.y += n0 * h0.y;
        acc.z += n0 * h0.z;
        acc.w += n0 * h0.w;
    }
    acc.x += __shfl_xor(acc.x, 16, 64);
    acc.y += __shfl_xor(acc.y, 16, 64);
    acc.z += __shfl_xor(acc.z, 16, 64);
    acc.w += __shfl_xor(acc.w, 16, 64);
    acc.x += __shfl_xor(acc.x, 32, 64);
    acc.y += __shfl_xor(acc.y, 32, 64);
    acc.z += __shfl_xor(acc.z, 32, 64);
    acc.w += __shfl_xor(acc.w, 32, 64);
    if (q == 0) {
        float di = dinv[i];
        float4 hv = h4[(size_t)i * 16 + c];
        float4 bv = ((const float4*)b)[c];
        float4 o;
        o.x = bv.x + di * (di * hv.x + acc.x);
        o.y = bv.y + di * (di * hv.y + acc.y);
        o.z = bv.z + di * (di * hv.z + acc.z);
        o.w = bv.w + di * (di * hv.w + acc.w);
        ((float4*)out)[(size_t)i * 16 + c] = o;
    }
}

// one wave per node, 32 ch: 8 slices x 8 lanes
__global__ void aggregate32(const float* __restrict__ h, const int* __restrict__ row_beg,
                            const int* __restrict__ row_cnt, const int* __restrict__ fsrc,
                            const float* __restrict__ fw, const float* __restrict__ dinv,
                            const float* __restrict__ b, float* __restrict__ out, int N) {
    int wv = threadIdx.x >> 6;
    int lane = threadIdx.x & 63;
    int sl = lane >> 3;
    int c = lane & 7;
    int i = blockIdx.x * 8 + wv;
    if (i >= N) return;
    int beg = row_beg[i];
    int end = beg + row_cnt[i];
    const float4* h4 = (const float4*)h;
    float4 acc = make_float4(0.f, 0.f, 0.f, 0.f);
    int e = beg + sl;
    for (; e + 8 < end; e += 16) {
        int s0 = fsrc[e];
        int s1 = fsrc[e + 8];
        float n0 = fw[e] * dinv[s0];
        float n1 = fw[e + 8] * dinv[s1];
        float4 h0 = h4[(size_t)s0 * 8 + c];
        float4 h1 = h4[(size_t)s1 * 8 + c];
        acc.x += n0 * h0.x + n1 * h1.x;
        acc.y += n0 * h0.y + n1 * h1.y;
        acc.z += n0 * h0.z + n1 * h1.z;
        acc.w += n0 * h0.w + n1 * h1.w;
    }
    if (e < end) {
        int s0 = fsrc[e];
        float n0 = fw[e] * dinv[s0];
        float4 h0 = h4[(size_t)s0 * 8 + c];
        acc.x += n0 * h0.x;
        acc.y += n0 * h0.y;
        acc.z += n0 * h0.z;
        acc.w += n0 * h0.w;
    }
    acc.x += __shfl_xor(acc.x, 8, 64);
    acc.y += __shfl_xor(acc.y, 8, 64);
    acc.z += __shfl_xor(acc.z, 8, 64);
    acc.w += __shfl_xor(acc.w, 8, 64);
    acc.x += __shfl_xor(acc.x, 16, 64);
    acc.y += __shfl_xor(acc.y, 16, 64);
    acc.z += __shfl_xor(acc.z, 16, 64);
    acc.w += __shfl_xor(acc.w, 16, 64);
    acc.x += __shfl_xor(acc.x, 32, 64);
    acc.y += __shfl_xor(acc.y, 32, 64);
    acc.z += __shfl_xor(acc.z, 32, 64);
    acc.w += __shfl_xor(acc.w, 32, 64);
    if (sl == 0) {
        float di = dinv[i];
        float4 hv = h4[(size_t)i * 8 + c];
        float4 bv = ((const float4*)b)[c];
        float4 o;
        o.x = bv.x + di * (di * hv.x + acc.x);
        o.y = bv.y + di * (di * hv.y + acc.y);
        o.z = bv.z + di * (di * hv.z + acc.z);
        o.w = bv.w + di * (di * hv.w + acc.w);
        ((float4*)out)[(size_t)i * 8 + c] = o;
    }
}

extern "C" void kernel_launch(void* const* d_in, const int* in_sizes, int n_in,
                              void* d_out, int out_size, void* d_ws, size_t ws_size,
                              hipStream_t stream) {
    const float* x  = (const float*)d_in[0];
    const int* eidx = (const int*)d_in[1];      // int64 in reference -> int32 on device
    const float* w  = (const float*)d_in[2];
    const float* W1 = (const float*)d_in[3];
    const float* b1 = (const float*)d_in[4];
    const float* W2 = (const float*)d_in[5];
    const float* b2 = (const float*)d_in[6];
    float* out = (float*)d_out;

    const int E = in_sizes[2];
    const int N = in_sizes[0] / 64;
    const int* src = eidx;
    const int* dst = eidx + E;
    const int NB = ceil_div(N, RNODES);          // 391 bins (must be <= 512)

    // workspace carve-up (256B-aligned): ~72 MB
    char* ws = (char*)d_ws;
    size_t off = 0;
    auto alloc = [&](size_t bytes) -> void* {
        void* p = ws + off;
        off = (off + bytes + 255) & ~(size_t)255;
        return p;
    };
    int*   bin_sizes  = (int*)alloc((size_t)NB * 4);
    int*   bin_cursor = (int*)alloc((size_t)NB * 4);
    int*   bin_start  = (int*)alloc((size_t)(NB + 1) * 4);
    int*   bp         = (int*)alloc((size_t)E * 4);     // binned packed (src<<8)|dstoff
    float* bw         = (float*)alloc((size_t)E * 4);   // binned weights
    int*   fsrc       = (int*)alloc((size_t)E * 4);     // final CSR src
    float* fw         = (float*)alloc((size_t)E * 4);   // final CSR weight
    int*   row_beg    = (int*)alloc((size_t)N * 4);
    int*   row_cnt    = (int*)alloc((size_t)N * 4);
    float* dinv       = (float*)alloc((size_t)N * 4);
    float* bufA       = (float*)alloc((size_t)N * 64 * 4);   // h1, then h2
    float* bufB       = (float*)alloc((size_t)N * 64 * 4);   // out1

    // build (no per-edge global atomics anywhere)
    zero_bins<<<1, 512, 0, stream>>>(bin_sizes, bin_cursor, NB);
    bin_count<<<96, 512, 0, stream>>>(dst, bin_sizes, NB, E);
    bin_scan<<<1, 512, 0, stream>>>(bin_sizes, bin_start, NB);
    bin_scatter<<<ceil_div(E, SC_E), SC_T, 0, stream>>>(src, dst, w, bin_cursor, bin_start,
                                                        bp, bw, NB, E);
    csr_build<<<NB, 512, 0, stream>>>(bp, bw, bin_start, row_beg, row_cnt, dinv, fsrc, fw, N, NB);

    // layer 1
    gemm_64_64<<<ceil_div(N, 16), 256, 0, stream>>>(x, W1, bufA, N);
    aggregate64<<<ceil_div(N, 8), 512, 0, stream>>>(bufA, row_beg, row_cnt, fsrc, fw, dinv, b1, bufB, N);

    // layer 2
    gemm_relu_64_32<<<ceil_div(N, 32), 256, 0, stream>>>(bufB, W2, bufA, N);
    aggregate32<<<ceil_div(N, 8), 512, 0, stream>>>(bufA, row_beg, row_cnt, fsrc, fw, dinv, b2, out, N);
}

// Round 7
// 257.626 us; speedup vs baseline: 6.6319x; 1.0590x over previous
//
#include <hip/hip_runtime.h>

static inline int ceil_div(long long a, long long b) { return (int)((a + b - 1) / b); }

// Node-range binning: bin = dst >> 8 (256 nodes per bin). N <= 131072 assumed (N=100000).
#define RBITS 8
#define RNODES 256

// bf16 helpers: pack with round-to-nearest-even, unpack via bit ops
__device__ inline unsigned f2bf(float f) {
    unsigned u = __float_as_uint(f);
    return (u + 0x7fffu + ((u >> 16) & 1u)) >> 16;
}
__device__ inline unsigned pack2(float a, float b) { return f2bf(a) | (f2bf(b) << 16); }
__device__ inline float bf_lo(unsigned v) { return __uint_as_float(v << 16); }
__device__ inline float bf_hi(unsigned v) { return __uint_as_float(v & 0xffff0000u); }

// ---------------- build step 0: zero bin counters ----------------
__global__ void zero_bins(int* __restrict__ bin_sizes, int* __restrict__ bin_cursor, int NB) {
    int t = threadIdx.x;
    for (int i = t; i < NB; i += 512) { bin_sizes[i] = 0; bin_cursor[i] = 0; }
}

// ---------------- step 1: per-bin edge counts (LDS histogram) ----------------
__global__ void bin_count(const int* __restrict__ dst, int* __restrict__ bin_sizes,
                          int NB, int E) {
    __shared__ int hist[512];
    int t = threadIdx.x;
    hist[t] = 0;
    __syncthreads();
    for (int e = blockIdx.x * 512 + t; e < E; e += gridDim.x * 512)
        atomicAdd(&hist[dst[e] >> RBITS], 1);
    __syncthreads();
    if (t < NB && hist[t]) atomicAdd(&bin_sizes[t], hist[t]);
}

// ---------------- step 2: exclusive scan of bin sizes (one block) ----------------
__global__ void bin_scan(const int* __restrict__ bin_sizes, int* __restrict__ bin_start, int NB) {
    __shared__ int s[512];
    int t = threadIdx.x;
    int v = (t < NB) ? bin_sizes[t] : 0;
    s[t] = v;
    __syncthreads();
    for (int d = 1; d < 512; d <<= 1) {
        int a = (t >= d) ? s[t - d] : 0;
        __syncthreads();
        s[t] += a;
        __syncthreads();
    }
    if (t < NB) bin_start[t] = s[t] - v;       // exclusive
    if (t == NB - 1) bin_start[NB] = s[t];     // total = E
}

// ---------------- step 3: partition edges into bins (LDS staging) ----------------
#define SC_T 512
#define SC_K 8
#define SC_E (SC_T * SC_K)   // 4096 edges per block
__global__ void bin_scatter(const int* __restrict__ src, const int* __restrict__ dst,
                            const float* __restrict__ w, int* __restrict__ bin_cursor,
                            const int* __restrict__ bin_start,
                            int* __restrict__ bp, float* __restrict__ bw,
                            int NB, int E) {
    __shared__ int hist[512];
    __shared__ int offs[512];     // inclusive scan of hist
    __shared__ int base[512];     // global write base per bin
    __shared__ int stage_p[SC_E];
    __shared__ float stage_w[SC_E];
    int t = threadIdx.x;
    hist[t] = 0;
    __syncthreads();
    int e0 = blockIdx.x * SC_E;
    int nE = E - e0; if (nE > SC_E) nE = SC_E;

    int myBin[SC_K], myRank[SC_K], myPack[SC_K];
    float myW[SC_K];
#pragma unroll
    for (int k = 0; k < SC_K; ++k) {
        int idx = t + k * SC_T;
        if (idx < nE) {
            int e = e0 + idx;
            int d = dst[e];
            int b = d >> RBITS;
            myBin[k] = b;
            myPack[k] = (src[e] << RBITS) | (d & (RNODES - 1));
            myW[k] = w[e];
            myRank[k] = atomicAdd(&hist[b], 1);
        }
    }
    __syncthreads();
    offs[t] = hist[t];
    __syncthreads();
    for (int d = 1; d < 512; d <<= 1) {
        int a = (t >= d) ? offs[t - d] : 0;
        __syncthreads();
        offs[t] += a;
        __syncthreads();
    }
    if (t < NB && hist[t]) base[t] = bin_start[t] + atomicAdd(&bin_cursor[t], hist[t]);
#pragma unroll
    for (int k = 0; k < SC_K; ++k) {
        int idx = t + k * SC_T;
        if (idx < nE) {
            int b = myBin[k];
            int pos = (offs[b] - hist[b]) + myRank[k];
            stage_p[pos] = myPack[k];
            stage_w[pos] = myW[k];
        }
    }
    __syncthreads();
    for (int p = t; p < nE; p += SC_T) {
        int lo = 0, hi = NB - 1;          // smallest b with offs[b] > p
        while (lo < hi) { int mid = (lo + hi) >> 1; if (offs[mid] > p) hi = mid; else lo = mid + 1; }
        int b = lo;
        int g = base[b] + (p - (offs[b] - hist[b]));
        bp[g] = stage_p[p];
        bw[g] = stage_w[p];
    }
}

// ---------------- step 4: per-bin counting sort -> dense CSR + dinv ----------------
__global__ void csr_build(const int* __restrict__ bp, const float* __restrict__ bw,
                          const int* __restrict__ bin_start,
                          int* __restrict__ row_beg, int* __restrict__ row_cnt,
                          float* __restrict__ dinv,
                          int* __restrict__ fsrc, float* __restrict__ fw,
                          int N, int NB) {
    __shared__ int cnt[RNODES];
    __shared__ float wsum[RNODES];
    __shared__ int starts[RNODES];
    __shared__ int cur[RNODES];
    int b = blockIdx.x;
    int t = threadIdx.x;   // 512
    if (t < RNODES) { cnt[t] = 0; wsum[t] = 0.f; }
    __syncthreads();
    int beg = bin_start[b], end = bin_start[b + 1];
    for (int e = beg + t; e < end; e += 512) {
        int off = bp[e] & (RNODES - 1);
        atomicAdd(&cnt[off], 1);
        atomicAdd(&wsum[off], bw[e]);
    }
    __syncthreads();
    if (t < RNODES) starts[t] = cnt[t];
    __syncthreads();
    for (int d = 1; d < RNODES; d <<= 1) {
        int a = 0;
        if (t < RNODES && t >= d) a = starts[t - d];
        __syncthreads();
        if (t < RNODES) starts[t] += a;
        __syncthreads();
    }
    if (t < RNODES) {
        int ex = starts[t] - cnt[t];
        cur[t] = beg + ex;
        int node = (b << RBITS) + t;
        if (node < N) {
            row_beg[node] = beg + ex;
            row_cnt[node] = cnt[t];
            dinv[node] = rsqrtf(wsum[t] + 1.0f);   // +1 = self-loop weight
        }
    }
    __syncthreads();
    for (int e = beg + t; e < end; e += 512) {
        int p = bp[e];
        int slot = atomicAdd(&cur[p & (RNODES - 1)], 1);
        fsrc[slot] = p >> RBITS;
        fw[slot] = bw[e];
    }
}

// ---------------- dense GEMMs -> packed bf16 output ----------------
// H[N x 64] bf16 = X[N x 64] @ W[64 x 64]
__global__ void gemm_64_64(const float* __restrict__ X, const float* __restrict__ W,
                           unsigned* __restrict__ H, int N) {
    __shared__ float Ws[64 * 64];
    int tid = threadIdx.x;
    for (int i = tid; i < 64 * 64; i += 256) Ws[i] = W[i];
    __syncthreads();
    int row = blockIdx.x * 16 + (tid >> 4);
    if (row >= N) return;
    int cg = (tid & 15) << 2;
    const float4* xrow = (const float4*)(X + (long long)row * 64);
    float4 acc = make_float4(0.f, 0.f, 0.f, 0.f);
#pragma unroll
    for (int kk = 0; kk < 16; ++kk) {
        float4 xv = xrow[kk];
        float xs[4] = {xv.x, xv.y, xv.z, xv.w};
#pragma unroll
        for (int j = 0; j < 4; ++j) {
            const float* wr = Ws + (kk * 4 + j) * 64 + cg;
            acc.x += xs[j] * wr[0];
            acc.y += xs[j] * wr[1];
            acc.z += xs[j] * wr[2];
            acc.w += xs[j] * wr[3];
        }
    }
    uint2 o = make_uint2(pack2(acc.x, acc.y), pack2(acc.z, acc.w));
    ((uint2*)(H + (size_t)row * 32))[tid & 15] = o;
}

// H[N x 32] bf16 = relu(X[N x 64]) @ W[64 x 32]
__global__ void gemm_relu_64_32(const float* __restrict__ X, const float* __restrict__ W,
                                unsigned* __restrict__ H, int N) {
    __shared__ float Ws[64 * 32];
    int tid = threadIdx.x;
    for (int i = tid; i < 64 * 32; i += 256) Ws[i] = W[i];
    __syncthreads();
    int row = blockIdx.x * 32 + (tid >> 3);
    if (row >= N) return;
    int cg = (tid & 7) << 2;
    const float4* xrow = (const float4*)(X + (long long)row * 64);
    float4 acc = make_float4(0.f, 0.f, 0.f, 0.f);
#pragma unroll
    for (int kk = 0; kk < 16; ++kk) {
        float4 xv = xrow[kk];
        float xs[4] = {fmaxf(xv.x, 0.f), fmaxf(xv.y, 0.f), fmaxf(xv.z, 0.f), fmaxf(xv.w, 0.f)};
#pragma unroll
        for (int j = 0; j < 4; ++j) {
            const float* wr = Ws + (kk * 4 + j) * 32 + cg;
            acc.x += xs[j] * wr[0];
            acc.y += xs[j] * wr[1];
            acc.z += xs[j] * wr[2];
            acc.w += xs[j] * wr[3];
        }
    }
    uint2 o = make_uint2(pack2(acc.x, acc.y), pack2(acc.z, acc.w));
    ((uint2*)(H + (size_t)row * 16))[tid & 7] = o;
}

// ---------------- aggregation (bf16 gather tables, fp32 accumulate) ----------------
// 64 ch: row = 32 uints = 8 x uint4. 8 slices x 8 lanes; 2x unroll -> 16 gathers in flight.
__global__ void aggregate64(const unsigned* __restrict__ h, const int* __restrict__ row_beg,
                            const int* __restrict__ row_cnt, const int* __restrict__ fsrc,
                            const float* __restrict__ fw, const float* __restrict__ dinv,
                            const float* __restrict__ b, float* __restrict__ out, int N) {
    int wv = threadIdx.x >> 6;
    int lane = threadIdx.x & 63;
    int sl = lane >> 3;               // slice 0..7
    int c = lane & 7;                 // uint4 index in row (8 ch per lane)
    int i = blockIdx.x * 8 + wv;
    if (i >= N) return;
    int beg = row_beg[i];
    int end = beg + row_cnt[i];
    const uint4* h4 = (const uint4*)h;
    float acc[8];
#pragma unroll
    for (int j = 0; j < 8; ++j) acc[j] = 0.f;
    int e = beg + sl;
    for (; e + 8 < end; e += 16) {
        int s0 = fsrc[e];
        int s1 = fsrc[e + 8];
        float n0 = fw[e] * dinv[s0];
        float n1 = fw[e + 8] * dinv[s1];
        uint4 v0 = h4[(size_t)s0 * 8 + c];
        uint4 v1 = h4[(size_t)s1 * 8 + c];
        acc[0] += n0 * bf_lo(v0.x) + n1 * bf_lo(v1.x);
        acc[1] += n0 * bf_hi(v0.x) + n1 * bf_hi(v1.x);
        acc[2] += n0 * bf_lo(v0.y) + n1 * bf_lo(v1.y);
        acc[3] += n0 * bf_hi(v0.y) + n1 * bf_hi(v1.y);
        acc[4] += n0 * bf_lo(v0.z) + n1 * bf_lo(v1.z);
        acc[5] += n0 * bf_hi(v0.z) + n1 * bf_hi(v1.z);
        acc[6] += n0 * bf_lo(v0.w) + n1 * bf_lo(v1.w);
        acc[7] += n0 * bf_hi(v0.w) + n1 * bf_hi(v1.w);
    }
    if (e < end) {
        int s0 = fsrc[e];
        float n0 = fw[e] * dinv[s0];
        uint4 v0 = h4[(size_t)s0 * 8 + c];
        acc[0] += n0 * bf_lo(v0.x);
        acc[1] += n0 * bf_hi(v0.x);
        acc[2] += n0 * bf_lo(v0.y);
        acc[3] += n0 * bf_hi(v0.y);
        acc[4] += n0 * bf_lo(v0.z);
        acc[5] += n0 * bf_hi(v0.z);
        acc[6] += n0 * bf_lo(v0.w);
        acc[7] += n0 * bf_hi(v0.w);
    }
#pragma unroll
    for (int m = 8; m <= 32; m <<= 1)
#pragma unroll
        for (int j = 0; j < 8; ++j) acc[j] += __shfl_xor(acc[j], m, 64);
    if (sl == 0) {
        float di = dinv[i];
        uint4 hv = h4[(size_t)i * 8 + c];
        float hs[8] = {bf_lo(hv.x), bf_hi(hv.x), bf_lo(hv.y), bf_hi(hv.y),
                       bf_lo(hv.z), bf_hi(hv.z), bf_lo(hv.w), bf_hi(hv.w)};
        float4 b0 = ((const float4*)b)[c * 2];
        float4 b1 = ((const float4*)b)[c * 2 + 1];
        float4 o0, o1;
        o0.x = b0.x + di * (di * hs[0] + acc[0]);
        o0.y = b0.y + di * (di * hs[1] + acc[1]);
        o0.z = b0.z + di * (di * hs[2] + acc[2]);
        o0.w = b0.w + di * (di * hs[3] + acc[3]);
        o1.x = b1.x + di * (di * hs[4] + acc[4]);
        o1.y = b1.y + di * (di * hs[5] + acc[5]);
        o1.z = b1.z + di * (di * hs[6] + acc[6]);
        o1.w = b1.w + di * (di * hs[7] + acc[7]);
        float4* op = (float4*)(out + (size_t)i * 64 + c * 8);
        op[0] = o0;
        op[1] = o1;
    }
}

// 32 ch: row = 16 uints = 4 x uint4. 16 slices x 4 lanes; 2x unroll -> 32 gathers in flight.
__global__ void aggregate32(const unsigned* __restrict__ h, const int* __restrict__ row_beg,
                            const int* __restrict__ row_cnt, const int* __restrict__ fsrc,
                            const float* __restrict__ fw, const float* __restrict__ dinv,
                            const float* __restrict__ b, float* __restrict__ out, int N) {
    int wv = threadIdx.x >> 6;
    int lane = threadIdx.x & 63;
    int sl = lane >> 2;               // slice 0..15
    int c = lane & 3;                 // uint4 index in row (8 ch per lane)
    int i = blockIdx.x * 8 + wv;
    if (i >= N) return;
    int beg = row_beg[i];
    int end = beg + row_cnt[i];
    const uint4* h4 = (const uint4*)h;
    float acc[8];
#pragma unroll
    for (int j = 0; j < 8; ++j) acc[j] = 0.f;
    int e = beg + sl;
    for (; e + 16 < end; e += 32) {
        int s0 = fsrc[e];
        int s1 = fsrc[e + 16];
        float n0 = fw[e] * dinv[s0];
        float n1 = fw[e + 16] * dinv[s1];
        uint4 v0 = h4[(size_t)s0 * 4 + c];
        uint4 v1 = h4[(size_t)s1 * 4 + c];
        acc[0] += n0 * bf_lo(v0.x) + n1 * bf_lo(v1.x);
        acc[1] += n0 * bf_hi(v0.x) + n1 * bf_hi(v1.x);
        acc[2] += n0 * bf_lo(v0.y) + n1 * bf_lo(v1.y);
        acc[3] += n0 * bf_hi(v0.y) + n1 * bf_hi(v1.y);
        acc[4] += n0 * bf_lo(v0.z) + n1 * bf_lo(v1.z);
        acc[5] += n0 * bf_hi(v0.z) + n1 * bf_hi(v1.z);
        acc[6] += n0 * bf_lo(v0.w) + n1 * bf_lo(v1.w);
        acc[7] += n0 * bf_hi(v0.w) + n1 * bf_hi(v1.w);
    }
    if (e < end) {
        int s0 = fsrc[e];
        float n0 = fw[e] * dinv[s0];
        uint4 v0 = h4[(size_t)s0 * 4 + c];
        acc[0] += n0 * bf_lo(v0.x);
        acc[1] += n0 * bf_hi(v0.x);
        acc[2] += n0 * bf_lo(v0.y);
        acc[3] += n0 * bf_hi(v0.y);
        acc[4] += n0 * bf_lo(v0.z);
        acc[5] += n0 * bf_hi(v0.z);
        acc[6] += n0 * bf_lo(v0.w);
        acc[7] += n0 * bf_hi(v0.w);
    }
#pragma unroll
    for (int m = 4; m <= 32; m <<= 1)
#pragma unroll
        for (int j = 0; j < 8; ++j) acc[j] += __shfl_xor(acc[j], m, 64);
    if (sl == 0) {
        float di = dinv[i];
        uint4 hv = h4[(size_t)i * 4 + c];
        float hs[8] = {bf_lo(hv.x), bf_hi(hv.x), bf_lo(hv.y), bf_hi(hv.y),
                       bf_lo(hv.z), bf_hi(hv.z), bf_lo(hv.w), bf_hi(hv.w)};
        float4 b0 = ((const float4*)b)[c * 2];
        float4 b1 = ((const float4*)b)[c * 2 + 1];
        float4 o0, o1;
        o0.x = b0.x + di * (di * hs[0] + acc[0]);
        o0.y = b0.y + di * (di * hs[1] + acc[1]);
        o0.z = b0.z + di * (di * hs[2] + acc[2]);
        o0.w = b0.w + di * (di * hs[3] + acc[3]);
        o1.x = b1.x + di * (di * hs[4] + acc[4]);
        o1.y = b1.y + di * (di * hs[5] + acc[5]);
        o1.z = b1.z + di * (di * hs[6] + acc[6]);
        o1.w = b1.w + di * (di * hs[7] + acc[7]);
        float4* op = (float4*)(out + (size_t)i * 32 + c * 8);
        op[0] = o0;
        op[1] = o1;
    }
}

extern "C" void kernel_launch(void* const* d_in, const int* in_sizes, int n_in,
                              void* d_out, int out_size, void* d_ws, size_t ws_size,
                              hipStream_t stream) {
    const float* x  = (const float*)d_in[0];
    const int* eidx = (const int*)d_in[1];      // int64 in reference -> int32 on device
    const float* w  = (const float*)d_in[2];
    const float* W1 = (const float*)d_in[3];
    const float* b1 = (const float*)d_in[4];
    const float* W2 = (const float*)d_in[5];
    const float* b2 = (const float*)d_in[6];
    float* out = (float*)d_out;

    const int E = in_sizes[2];
    const int N = in_sizes[0] / 64;
    const int* src = eidx;
    const int* dst = eidx + E;
    const int NB = ceil_div(N, RNODES);          // 391 bins (must be <= 512)

    // workspace carve-up (256B-aligned)
    char* ws = (char*)d_ws;
    size_t off = 0;
    auto alloc = [&](size_t bytes) -> void* {
        void* p = ws + off;
        off = (off + bytes + 255) & ~(size_t)255;
        return p;
    };
    int*      bin_sizes  = (int*)alloc((size_t)NB * 4);
    int*      bin_cursor = (int*)alloc((size_t)NB * 4);
    int*      bin_start  = (int*)alloc((size_t)(NB + 1) * 4);
    int*      bp         = (int*)alloc((size_t)E * 4);     // binned packed (src<<8)|dstoff
    float*    bw         = (float*)alloc((size_t)E * 4);   // binned weights
    int*      fsrc       = (int*)alloc((size_t)E * 4);     // final CSR src
    float*    fw         = (float*)alloc((size_t)E * 4);   // final CSR weight
    int*      row_beg    = (int*)alloc((size_t)N * 4);
    int*      row_cnt    = (int*)alloc((size_t)N * 4);
    float*    dinv       = (float*)alloc((size_t)N * 4);
    unsigned* h1         = (unsigned*)alloc((size_t)N * 32 * 4);  // bf16 N x 64
    unsigned* h2         = (unsigned*)alloc((size_t)N * 16 * 4);  // bf16 N x 32
    float*    out1       = (float*)alloc((size_t)N * 64 * 4);     // fp32 layer-1 output

    // build (no per-edge global atomics anywhere)
    zero_bins<<<1, 512, 0, stream>>>(bin_sizes, bin_cursor, NB);
    bin_count<<<96, 512, 0, stream>>>(dst, bin_sizes, NB, E);
    bin_scan<<<1, 512, 0, stream>>>(bin_sizes, bin_start, NB);
    bin_scatter<<<ceil_div(E, SC_E), SC_T, 0, stream>>>(src, dst, w, bin_cursor, bin_start,
                                                        bp, bw, NB, E);
    csr_build<<<NB, 512, 0, stream>>>(bp, bw, bin_start, row_beg, row_cnt, dinv, fsrc, fw, N, NB);

    // layer 1
    gemm_64_64<<<ceil_div(N, 16), 256, 0, stream>>>(x, W1, h1, N);
    aggregate64<<<ceil_div(N, 8), 512, 0, stream>>>(h1, row_beg, row_cnt, fsrc, fw, dinv, b1, out1, N);

    // layer 2
    gemm_relu_64_32<<<ceil_div(N, 32), 256, 0, stream>>>(out1, W2, h2, N);
    aggregate32<<<ceil_div(N, 8), 512, 0, stream>>>(h2, row_beg, row_cnt, fsrc, fw, dinv, b2, out, N);
}

// Round 8
// 245.255 us; speedup vs baseline: 6.9664x; 1.0504x over previous
//
#include <hip/hip_runtime.h>

static inline int ceil_div(long long a, long long b) { return (int)((a + b - 1) / b); }

// Node-range binning: bin = dst >> 8 (256 nodes per bin). N <= 131072 assumed (N=100000).
#define RBITS 8
#define RNODES 256

typedef __attribute__((ext_vector_type(8))) short bf16x8;
typedef __attribute__((ext_vector_type(4))) float f32x4;

// bf16 helpers: pack with round-to-nearest-even, unpack via bit ops
__device__ inline unsigned f2bf(float f) {
    unsigned u = __float_as_uint(f);
    return (u + 0x7fffu + ((u >> 16) & 1u)) >> 16;
}
__device__ inline float bf2f(unsigned v) { return __uint_as_float(v << 16); }
__device__ inline float bf_lo(unsigned v) { return __uint_as_float(v << 16); }
__device__ inline float bf_hi(unsigned v) { return __uint_as_float(v & 0xffff0000u); }

// ---------------- build step 0: zero bin counters ----------------
__global__ void zero_bins(int* __restrict__ bin_sizes, int* __restrict__ bin_cursor, int NB) {
    int t = threadIdx.x;
    for (int i = t; i < NB; i += 512) { bin_sizes[i] = 0; bin_cursor[i] = 0; }
}

// ---------------- step 1: per-bin edge counts (LDS histogram) ----------------
__global__ void bin_count(const int* __restrict__ dst, int* __restrict__ bin_sizes,
                          int NB, int E) {
    __shared__ int hist[512];
    int t = threadIdx.x;
    hist[t] = 0;
    __syncthreads();
    for (int e = blockIdx.x * 512 + t; e < E; e += gridDim.x * 512)
        atomicAdd(&hist[dst[e] >> RBITS], 1);
    __syncthreads();
    if (t < NB && hist[t]) atomicAdd(&bin_sizes[t], hist[t]);
}

// ---------------- step 2: exclusive scan of bin sizes (one block) ----------------
__global__ void bin_scan(const int* __restrict__ bin_sizes, int* __restrict__ bin_start, int NB) {
    __shared__ int s[512];
    int t = threadIdx.x;
    int v = (t < NB) ? bin_sizes[t] : 0;
    s[t] = v;
    __syncthreads();
    for (int d = 1; d < 512; d <<= 1) {
        int a = (t >= d) ? s[t - d] : 0;
        __syncthreads();
        s[t] += a;
        __syncthreads();
    }
    if (t < NB) bin_start[t] = s[t] - v;       // exclusive
    if (t == NB - 1) bin_start[NB] = s[t];     // total = E
}

// ---------------- step 3: partition edges into bins (LDS staging) ----------------
#define SC_T 512
#define SC_K 8
#define SC_E (SC_T * SC_K)   // 4096 edges per block
__global__ void bin_scatter(const int* __restrict__ src, const int* __restrict__ dst,
                            const float* __restrict__ w, int* __restrict__ bin_cursor,
                            const int* __restrict__ bin_start,
                            int* __restrict__ bp, float* __restrict__ bw,
                            int NB, int E) {
    __shared__ int hist[512];
    __shared__ int offs[512];     // inclusive scan of hist
    __shared__ int base[512];     // global write base per bin
    __shared__ int stage_p[SC_E];
    __shared__ float stage_w[SC_E];
    int t = threadIdx.x;
    hist[t] = 0;
    __syncthreads();
    int e0 = blockIdx.x * SC_E;
    int nE = E - e0; if (nE > SC_E) nE = SC_E;

    int myBin[SC_K], myRank[SC_K], myPack[SC_K];
    float myW[SC_K];
#pragma unroll
    for (int k = 0; k < SC_K; ++k) {
        int idx = t + k * SC_T;
        if (idx < nE) {
            int e = e0 + idx;
            int d = dst[e];
            int b = d >> RBITS;
            myBin[k] = b;
            myPack[k] = (src[e] << RBITS) | (d & (RNODES - 1));
            myW[k] = w[e];
            myRank[k] = atomicAdd(&hist[b], 1);
        }
    }
    __syncthreads();
    offs[t] = hist[t];
    __syncthreads();
    for (int d = 1; d < 512; d <<= 1) {
        int a = (t >= d) ? offs[t - d] : 0;
        __syncthreads();
        offs[t] += a;
        __syncthreads();
    }
    if (t < NB && hist[t]) base[t] = bin_start[t] + atomicAdd(&bin_cursor[t], hist[t]);
#pragma unroll
    for (int k = 0; k < SC_K; ++k) {
        int idx = t + k * SC_T;
        if (idx < nE) {
            int b = myBin[k];
            int pos = (offs[b] - hist[b]) + myRank[k];
            stage_p[pos] = myPack[k];
            stage_w[pos] = myW[k];
        }
    }
    __syncthreads();
    for (int p = t; p < nE; p += SC_T) {
        int lo = 0, hi = NB - 1;          // smallest b with offs[b] > p
        while (lo < hi) { int mid = (lo + hi) >> 1; if (offs[mid] > p) hi = mid; else lo = mid + 1; }
        int b = lo;
        int g = base[b] + (p - (offs[b] - hist[b]));
        bp[g] = stage_p[p];
        bw[g] = stage_w[p];
    }
}

// ---------------- step 4: per-bin counting sort -> dense CSR + dinv ----------------
__global__ void csr_build(const int* __restrict__ bp, const float* __restrict__ bw,
                          const int* __restrict__ bin_start,
                          int* __restrict__ row_beg, int* __restrict__ row_cnt,
                          float* __restrict__ dinv,
                          int* __restrict__ fsrc, float* __restrict__ fw,
                          int N, int NB) {
    __shared__ int cnt[RNODES];
    __shared__ float wsum[RNODES];
    __shared__ int starts[RNODES];
    __shared__ int cur[RNODES];
    int b = blockIdx.x;
    int t = threadIdx.x;   // 512
    if (t < RNODES) { cnt[t] = 0; wsum[t] = 0.f; }
    __syncthreads();
    int beg = bin_start[b], end = bin_start[b + 1];
    for (int e = beg + t; e < end; e += 512) {
        int off = bp[e] & (RNODES - 1);
        atomicAdd(&cnt[off], 1);
        atomicAdd(&wsum[off], bw[e]);
    }
    __syncthreads();
    if (t < RNODES) starts[t] = cnt[t];
    __syncthreads();
    for (int d = 1; d < RNODES; d <<= 1) {
        int a = 0;
        if (t < RNODES && t >= d) a = starts[t - d];
        __syncthreads();
        if (t < RNODES) starts[t] += a;
        __syncthreads();
    }
    if (t < RNODES) {
        int ex = starts[t] - cnt[t];
        cur[t] = beg + ex;
        int node = (b << RBITS) + t;
        if (node < N) {
            row_beg[node] = beg + ex;
            row_cnt[node] = cnt[t];
            dinv[node] = rsqrtf(wsum[t] + 1.0f);   // +1 = self-loop weight
        }
    }
    __syncthreads();
    for (int e = beg + t; e < end; e += 512) {
        int p = bp[e];
        int slot = atomicAdd(&cur[p & (RNODES - 1)], 1);
        fsrc[slot] = p >> RBITS;
        fw[slot] = bw[e];
    }
}

// ---------------- MFMA GEMMs (split-bf16 3-product, near-fp32 accuracy) ----------------
// Verified 16x16x32_bf16 layout (guide m89/m91):
//   A[m = lane&15][k = (lane>>4)*8 + j],  B[k = (lane>>4)*8 + j][n = lane&15],
//   D: col = lane&15, row = (lane>>4)*4 + reg.
// Each wave: all B-frags of W in registers; 4 row-tiles of 16 rows; output stored bf16.

// H1[N x 64] bf16 = X[N x 64] fp32 @ W[64 x 64] fp32
__global__ __launch_bounds__(256) void gemm1_mfma(const float* __restrict__ X,
                                                  const float* __restrict__ W,
                                                  unsigned short* __restrict__ H, int N) {
    int lane = threadIdx.x & 63;
    int wv = threadIdx.x >> 6;
    int quad = lane >> 4;
    int col = lane & 15;

    bf16x8 Bh[4][2], Bl[4][2];
#pragma unroll
    for (int nt = 0; nt < 4; ++nt)
#pragma unroll
        for (int kh = 0; kh < 2; ++kh)
#pragma unroll
            for (int j = 0; j < 8; ++j) {
                float wval = W[(kh * 32 + quad * 8 + j) * 64 + nt * 16 + col];
                unsigned hb = f2bf(wval);
                Bh[nt][kh][j] = (short)hb;
                Bl[nt][kh][j] = (short)f2bf(wval - bf2f(hb));
            }

#pragma unroll
    for (int rt = 0; rt < 4; ++rt) {
        int rb = blockIdx.x * 256 + wv * 64 + rt * 16;
        if (rb >= N) break;                       // wave-uniform
        int arow = rb + col;                      // col doubles as A's m index
        bf16x8 Ah[2], Al[2];
#pragma unroll
        for (int kh = 0; kh < 2; ++kh) {
            float xv[8];
            if (arow < N) {
                const float4* p = (const float4*)(X + (size_t)arow * 64 + kh * 32 + quad * 8);
                float4 f0 = p[0], f1 = p[1];
                xv[0] = f0.x; xv[1] = f0.y; xv[2] = f0.z; xv[3] = f0.w;
                xv[4] = f1.x; xv[5] = f1.y; xv[6] = f1.z; xv[7] = f1.w;
            } else {
#pragma unroll
                for (int j = 0; j < 8; ++j) xv[j] = 0.f;
            }
#pragma unroll
            for (int j = 0; j < 8; ++j) {
                unsigned hb = f2bf(xv[j]);
                Ah[kh][j] = (short)hb;
                Al[kh][j] = (short)f2bf(xv[j] - bf2f(hb));
            }
        }
        f32x4 acc[4] = {{0,0,0,0},{0,0,0,0},{0,0,0,0},{0,0,0,0}};
#pragma unroll
        for (int nt = 0; nt < 4; ++nt)
#pragma unroll
            for (int kh = 0; kh < 2; ++kh) {
                acc[nt] = __builtin_amdgcn_mfma_f32_16x16x32_bf16(Ah[kh], Bh[nt][kh], acc[nt], 0, 0, 0);
                acc[nt] = __builtin_amdgcn_mfma_f32_16x16x32_bf16(Al[kh], Bh[nt][kh], acc[nt], 0, 0, 0);
                acc[nt] = __builtin_amdgcn_mfma_f32_16x16x32_bf16(Ah[kh], Bl[nt][kh], acc[nt], 0, 0, 0);
            }
#pragma unroll
        for (int nt = 0; nt < 4; ++nt)
#pragma unroll
            for (int r = 0; r < 4; ++r) {
                int row = rb + quad * 4 + r;
                if (row < N)
                    H[(size_t)row * 64 + nt * 16 + col] = (unsigned short)f2bf(acc[nt][r]);
            }
    }
}

// H2[N x 32] bf16 = relu(X[N x 64] fp32) @ W[64 x 32] fp32
__global__ __launch_bounds__(256) void gemm2_mfma(const float* __restrict__ X,
                                                  const float* __restrict__ W,
                                                  unsigned short* __restrict__ H, int N) {
    int lane = threadIdx.x & 63;
    int wv = threadIdx.x >> 6;
    int quad = lane >> 4;
    int col = lane & 15;

    bf16x8 Bh[2][2], Bl[2][2];
#pragma unroll
    for (int nt = 0; nt < 2; ++nt)
#pragma unroll
        for (int kh = 0; kh < 2; ++kh)
#pragma unroll
            for (int j = 0; j < 8; ++j) {
                float wval = W[(kh * 32 + quad * 8 + j) * 32 + nt * 16 + col];
                unsigned hb = f2bf(wval);
                Bh[nt][kh][j] = (short)hb;
                Bl[nt][kh][j] = (short)f2bf(wval - bf2f(hb));
            }

#pragma unroll
    for (int rt = 0; rt < 4; ++rt) {
        int rb = blockIdx.x * 256 + wv * 64 + rt * 16;
        if (rb >= N) break;
        int arow = rb + col;
        bf16x8 Ah[2], Al[2];
#pragma unroll
        for (int kh = 0; kh < 2; ++kh) {
            float xv[8];
            if (arow < N) {
                const float4* p = (const float4*)(X + (size_t)arow * 64 + kh * 32 + quad * 8);
                float4 f0 = p[0], f1 = p[1];
                xv[0] = f0.x; xv[1] = f0.y; xv[2] = f0.z; xv[3] = f0.w;
                xv[4] = f1.x; xv[5] = f1.y; xv[6] = f1.z; xv[7] = f1.w;
            } else {
#pragma unroll
                for (int j = 0; j < 8; ++j) xv[j] = 0.f;
            }
#pragma unroll
            for (int j = 0; j < 8; ++j) {
                float xr = fmaxf(xv[j], 0.f);     // fused relu
                unsigned hb = f2bf(xr);
                Ah[kh][j] = (short)hb;
                Al[kh][j] = (short)f2bf(xr - bf2f(hb));
            }
        }
        f32x4 acc[2] = {{0,0,0,0},{0,0,0,0}};
#pragma unroll
        for (int nt = 0; nt < 2; ++nt)
#pragma unroll
            for (int kh = 0; kh < 2; ++kh) {
                acc[nt] = __builtin_amdgcn_mfma_f32_16x16x32_bf16(Ah[kh], Bh[nt][kh], acc[nt], 0, 0, 0);
                acc[nt] = __builtin_amdgcn_mfma_f32_16x16x32_bf16(Al[kh], Bh[nt][kh], acc[nt], 0, 0, 0);
                acc[nt] = __builtin_amdgcn_mfma_f32_16x16x32_bf16(Ah[kh], Bl[nt][kh], acc[nt], 0, 0, 0);
            }
#pragma unroll
        for (int nt = 0; nt < 2; ++nt)
#pragma unroll
            for (int r = 0; r < 4; ++r) {
                int row = rb + quad * 4 + r;
                if (row < N)
                    H[(size_t)row * 32 + nt * 16 + col] = (unsigned short)f2bf(acc[nt][r]);
            }
    }
}

// ---------------- aggregation (bf16 gather tables, fp32 accumulate) ----------------
// 64 ch: row = 32 uints = 8 x uint4. 8 slices x 8 lanes; 2x unroll -> 16 gathers in flight.
__global__ void aggregate64(const unsigned* __restrict__ h, const int* __restrict__ row_beg,
                            const int* __restrict__ row_cnt, const int* __restrict__ fsrc,
                            const float* __restrict__ fw, const float* __restrict__ dinv,
                            const float* __restrict__ b, float* __restrict__ out, int N) {
    int wv = threadIdx.x >> 6;
    int lane = threadIdx.x & 63;
    int sl = lane >> 3;               // slice 0..7
    int c = lane & 7;                 // uint4 index in row (8 ch per lane)
    int i = blockIdx.x * 8 + wv;
    if (i >= N) return;
    int beg = row_beg[i];
    int end = beg + row_cnt[i];
    const uint4* h4 = (const uint4*)h;
    float acc[8];
#pragma unroll
    for (int j = 0; j < 8; ++j) acc[j] = 0.f;
    int e = beg + sl;
    for (; e + 8 < end; e += 16) {
        int s0 = fsrc[e];
        int s1 = fsrc[e + 8];
        float n0 = fw[e] * dinv[s0];
        float n1 = fw[e + 8] * dinv[s1];
        uint4 v0 = h4[(size_t)s0 * 8 + c];
        uint4 v1 = h4[(size_t)s1 * 8 + c];
        acc[0] += n0 * bf_lo(v0.x) + n1 * bf_lo(v1.x);
        acc[1] += n0 * bf_hi(v0.x) + n1 * bf_hi(v1.x);
        acc[2] += n0 * bf_lo(v0.y) + n1 * bf_lo(v1.y);
        acc[3] += n0 * bf_hi(v0.y) + n1 * bf_hi(v1.y);
        acc[4] += n0 * bf_lo(v0.z) + n1 * bf_lo(v1.z);
        acc[5] += n0 * bf_hi(v0.z) + n1 * bf_hi(v1.z);
        acc[6] += n0 * bf_lo(v0.w) + n1 * bf_lo(v1.w);
        acc[7] += n0 * bf_hi(v0.w) + n1 * bf_hi(v1.w);
    }
    if (e < end) {
        int s0 = fsrc[e];
        float n0 = fw[e] * dinv[s0];
        uint4 v0 = h4[(size_t)s0 * 8 + c];
        acc[0] += n0 * bf_lo(v0.x);
        acc[1] += n0 * bf_hi(v0.x);
        acc[2] += n0 * bf_lo(v0.y);
        acc[3] += n0 * bf_hi(v0.y);
        acc[4] += n0 * bf_lo(v0.z);
        acc[5] += n0 * bf_hi(v0.z);
        acc[6] += n0 * bf_lo(v0.w);
        acc[7] += n0 * bf_hi(v0.w);
    }
#pragma unroll
    for (int m = 8; m <= 32; m <<= 1)
#pragma unroll
        for (int j = 0; j < 8; ++j) acc[j] += __shfl_xor(acc[j], m, 64);
    if (sl == 0) {
        float di = dinv[i];
        uint4 hv = h4[(size_t)i * 8 + c];
        float hs[8] = {bf_lo(hv.x), bf_hi(hv.x), bf_lo(hv.y), bf_hi(hv.y),
                       bf_lo(hv.z), bf_hi(hv.z), bf_lo(hv.w), bf_hi(hv.w)};
        float4 b0 = ((const float4*)b)[c * 2];
        float4 b1 = ((const float4*)b)[c * 2 + 1];
        float4 o0, o1;
        o0.x = b0.x + di * (di * hs[0] + acc[0]);
        o0.y = b0.y + di * (di * hs[1] + acc[1]);
        o0.z = b0.z + di * (di * hs[2] + acc[2]);
        o0.w = b0.w + di * (di * hs[3] + acc[3]);
        o1.x = b1.x + di * (di * hs[4] + acc[4]);
        o1.y = b1.y + di * (di * hs[5] + acc[5]);
        o1.z = b1.z + di * (di * hs[6] + acc[6]);
        o1.w = b1.w + di * (di * hs[7] + acc[7]);
        float4* op = (float4*)(out + (size_t)i * 64 + c * 8);
        op[0] = o0;
        op[1] = o1;
    }
}

// 32 ch: row = 16 uints = 4 x uint4. 16 slices x 4 lanes; 2x unroll -> 32 gathers in flight.
__global__ void aggregate32(const unsigned* __restrict__ h, const int* __restrict__ row_beg,
                            const int* __restrict__ row_cnt, const int* __restrict__ fsrc,
                            const float* __restrict__ fw, const float* __restrict__ dinv,
                            const float* __restrict__ b, float* __restrict__ out, int N) {
    int wv = threadIdx.x >> 6;
    int lane = threadIdx.x & 63;
    int sl = lane >> 2;               // slice 0..15
    int c = lane & 3;                 // uint4 index in row (8 ch per lane)
    int i = blockIdx.x * 8 + wv;
    if (i >= N) return;
    int beg = row_beg[i];
    int end = beg + row_cnt[i];
    const uint4* h4 = (const uint4*)h;
    float acc[8];
#pragma unroll
    for (int j = 0; j < 8; ++j) acc[j] = 0.f;
    int e = beg + sl;
    for (; e + 16 < end; e += 32) {
        int s0 = fsrc[e];
        int s1 = fsrc[e + 16];
        float n0 = fw[e] * dinv[s0];
        float n1 = fw[e + 16] * dinv[s1];
        uint4 v0 = h4[(size_t)s0 * 4 + c];
        uint4 v1 = h4[(size_t)s1 * 4 + c];
        acc[0] += n0 * bf_lo(v0.x) + n1 * bf_lo(v1.x);
        acc[1] += n0 * bf_hi(v0.x) + n1 * bf_hi(v1.x);
        acc[2] += n0 * bf_lo(v0.y) + n1 * bf_lo(v1.y);
        acc[3] += n0 * bf_hi(v0.y) + n1 * bf_hi(v1.y);
        acc[4] += n0 * bf_lo(v0.z) + n1 * bf_lo(v1.z);
        acc[5] += n0 * bf_hi(v0.z) + n1 * bf_hi(v1.z);
        acc[6] += n0 * bf_lo(v0.w) + n1 * bf_lo(v1.w);
        acc[7] += n0 * bf_hi(v0.w) + n1 * bf_hi(v1.w);
    }
    if (e < end) {
        int s0 = fsrc[e];
        float n0 = fw[e] * dinv[s0];
        uint4 v0 = h4[(size_t)s0 * 4 + c];
        acc[0] += n0 * bf_lo(v0.x);
        acc[1] += n0 * bf_hi(v0.x);
        acc[2] += n0 * bf_lo(v0.y);
        acc[3] += n0 * bf_hi(v0.y);
        acc[4] += n0 * bf_lo(v0.z);
        acc[5] += n0 * bf_hi(v0.z);
        acc[6] += n0 * bf_lo(v0.w);
        acc[7] += n0 * bf_hi(v0.w);
    }
#pragma unroll
    for (int m = 4; m <= 32; m <<= 1)
#pragma unroll
        for (int j = 0; j < 8; ++j) acc[j] += __shfl_xor(acc[j], m, 64);
    if (sl == 0) {
        float di = dinv[i];
        uint4 hv = h4[(size_t)i * 4 + c];
        float hs[8] = {bf_lo(hv.x), bf_hi(hv.x), bf_lo(hv.y), bf_hi(hv.y),
                       bf_lo(hv.z), bf_hi(hv.z), bf_lo(hv.w), bf_hi(hv.w)};
        float4 b0 = ((const float4*)b)[c * 2];
        float4 b1 = ((const float4*)b)[c * 2 + 1];
        float4 o0, o1;
        o0.x = b0.x + di * (di * hs[0] + acc[0]);
        o0.y = b0.y + di * (di * hs[1] + acc[1]);
        o0.z = b0.z + di * (di * hs[2] + acc[2]);
        o0.w = b0.w + di * (di * hs[3] + acc[3]);
        o1.x = b1.x + di * (di * hs[4] + acc[4]);
        o1.y = b1.y + di * (di * hs[5] + acc[5]);
        o1.z = b1.z + di * (di * hs[6] + acc[6]);
        o1.w = b1.w + di * (di * hs[7] + acc[7]);
        float4* op = (float4*)(out + (size_t)i * 32 + c * 8);
        op[0] = o0;
        op[1] = o1;
    }
}

extern "C" void kernel_launch(void* const* d_in, const int* in_sizes, int n_in,
                              void* d_out, int out_size, void* d_ws, size_t ws_size,
                              hipStream_t stream) {
    const float* x  = (const float*)d_in[0];
    const int* eidx = (const int*)d_in[1];      // int64 in reference -> int32 on device
    const float* w  = (const float*)d_in[2];
    const float* W1 = (const float*)d_in[3];
    const float* b1 = (const float*)d_in[4];
    const float* W2 = (const float*)d_in[5];
    const float* b2 = (const float*)d_in[6];
    float* out = (float*)d_out;

    const int E = in_sizes[2];
    const int N = in_sizes[0] / 64;
    const int* src = eidx;
    const int* dst = eidx + E;
    const int NB = ceil_div(N, RNODES);          // 391 bins (must be <= 512)

    // workspace carve-up (256B-aligned)
    char* ws = (char*)d_ws;
    size_t off = 0;
    auto alloc = [&](size_t bytes) -> void* {
        void* p = ws + off;
        off = (off + bytes + 255) & ~(size_t)255;
        return p;
    };
    int*      bin_sizes  = (int*)alloc((size_t)NB * 4);
    int*      bin_cursor = (int*)alloc((size_t)NB * 4);
    int*      bin_start  = (int*)alloc((size_t)(NB + 1) * 4);
    int*      bp         = (int*)alloc((size_t)E * 4);     // binned packed (src<<8)|dstoff
    float*    bw         = (float*)alloc((size_t)E * 4);   // binned weights
    int*      fsrc       = (int*)alloc((size_t)E * 4);     // final CSR src
    float*    fw         = (float*)alloc((size_t)E * 4);   // final CSR weight
    int*      row_beg    = (int*)alloc((size_t)N * 4);
    int*      row_cnt    = (int*)alloc((size_t)N * 4);
    float*    dinv       = (float*)alloc((size_t)N * 4);
    unsigned* h1         = (unsigned*)alloc((size_t)N * 32 * 4);  // bf16 N x 64
    unsigned* h2         = (unsigned*)alloc((size_t)N * 16 * 4);  // bf16 N x 32
    float*    out1       = (float*)alloc((size_t)N * 64 * 4);     // fp32 layer-1 output

    // build (no per-edge global atomics anywhere)
    zero_bins<<<1, 512, 0, stream>>>(bin_sizes, bin_cursor, NB);
    bin_count<<<96, 512, 0, stream>>>(dst, bin_sizes, NB, E);
    bin_scan<<<1, 512, 0, stream>>>(bin_sizes, bin_start, NB);
    bin_scatter<<<ceil_div(E, SC_E), SC_T, 0, stream>>>(src, dst, w, bin_cursor, bin_start,
                                                        bp, bw, NB, E);
    csr_build<<<NB, 512, 0, stream>>>(bp, bw, bin_start, row_beg, row_cnt, dinv, fsrc, fw, N, NB);

    // layer 1 (MFMA gemm -> bf16 table)
    gemm1_mfma<<<ceil_div(N, 256), 256, 0, stream>>>(x, W1, (unsigned short*)h1, N);
    aggregate64<<<ceil_div(N, 8), 512, 0, stream>>>(h1, row_beg, row_cnt, fsrc, fw, dinv, b1, out1, N);

    // layer 2 (fused relu + MFMA gemm -> bf16 table)
    gemm2_mfma<<<ceil_div(N, 256), 256, 0, stream>>>(out1, W2, (unsigned short*)h2, N);
    aggregate32<<<ceil_div(N, 8), 512, 0, stream>>>(h2, row_beg, row_cnt, fsrc, fw, dinv, b2, out, N);
}

// Round 9
// 217.378 us; speedup vs baseline: 7.8598x; 1.1282x over previous
//
#include <hip/hip_runtime.h>

static inline int ceil_div(long long a, long long b) { return (int)((a + b - 1) / b); }

// Node-range binning: bin = dst >> 8 (256 nodes per bin). N <= 131072 assumed (N=100000).
#define RBITS 8
#define RNODES 256

typedef __attribute__((ext_vector_type(8))) short bf16x8;
typedef __attribute__((ext_vector_type(4))) float f32x4;

// bf16 helpers: pack with round-to-nearest-even, unpack via bit ops
__device__ inline unsigned f2bf(float f) {
    unsigned u = __float_as_uint(f);
    return (u + 0x7fffu + ((u >> 16) & 1u)) >> 16;
}
__device__ inline float bf2f(unsigned v) { return __uint_as_float(v << 16); }
__device__ inline float bf_lo(unsigned v) { return __uint_as_float(v << 16); }
__device__ inline float bf_hi(unsigned v) { return __uint_as_float(v & 0xffff0000u); }

// ---------------- build step 0: zero bin counters ----------------
__global__ void zero_bins(int* __restrict__ bin_sizes, int* __restrict__ bin_cursor, int NB) {
    int t = threadIdx.x;
    for (int i = t; i < NB; i += 512) { bin_sizes[i] = 0; bin_cursor[i] = 0; }
}

// ---------------- step 1: per-bin edge counts (LDS histogram) ----------------
__global__ void bin_count(const int* __restrict__ dst, int* __restrict__ bin_sizes,
                          int NB, int E) {
    __shared__ int hist[512];
    int t = threadIdx.x;
    hist[t] = 0;
    __syncthreads();
    for (int e = blockIdx.x * 512 + t; e < E; e += gridDim.x * 512)
        atomicAdd(&hist[dst[e] >> RBITS], 1);
    __syncthreads();
    if (t < NB && hist[t]) atomicAdd(&bin_sizes[t], hist[t]);
}

// ---------------- step 2: exclusive scan of bin sizes (one block) ----------------
__global__ void bin_scan(const int* __restrict__ bin_sizes, int* __restrict__ bin_start, int NB) {
    __shared__ int s[512];
    int t = threadIdx.x;
    int v = (t < NB) ? bin_sizes[t] : 0;
    s[t] = v;
    __syncthreads();
    for (int d = 1; d < 512; d <<= 1) {
        int a = (t >= d) ? s[t - d] : 0;
        __syncthreads();
        s[t] += a;
        __syncthreads();
    }
    if (t < NB) bin_start[t] = s[t] - v;       // exclusive
    if (t == NB - 1) bin_start[NB] = s[t];     // total = E
}

// ---------------- step 3: partition edges into bins (LDS staging) ----------------
#define SC_T 512
#define SC_K 8
#define SC_E (SC_T * SC_K)   // 4096 edges per block
__global__ void bin_scatter(const int* __restrict__ src, const int* __restrict__ dst,
                            const float* __restrict__ w, int* __restrict__ bin_cursor,
                            const int* __restrict__ bin_start,
                            int* __restrict__ bp, float* __restrict__ bw,
                            int NB, int E) {
    __shared__ int hist[512];
    __shared__ int offs[512];               // inclusive scan of hist
    __shared__ int base[512];               // global write base per bin
    __shared__ int stage_p[SC_E];
    __shared__ float stage_w[SC_E];
    __shared__ unsigned short stage_b[SC_E]; // bin id per staged slot (kills the binary search)
    int t = threadIdx.x;
    hist[t] = 0;
    __syncthreads();
    int e0 = blockIdx.x * SC_E;
    int nE = E - e0; if (nE > SC_E) nE = SC_E;

    int myBin[SC_K], myRank[SC_K], myPack[SC_K];
    float myW[SC_K];
#pragma unroll
    for (int k = 0; k < SC_K; ++k) {
        int idx = t + k * SC_T;
        if (idx < nE) {
            int e = e0 + idx;
            int d = dst[e];
            int b = d >> RBITS;
            myBin[k] = b;
            myPack[k] = (src[e] << RBITS) | (d & (RNODES - 1));
            myW[k] = w[e];
            myRank[k] = atomicAdd(&hist[b], 1);
        }
    }
    __syncthreads();
    offs[t] = hist[t];
    __syncthreads();
    for (int d = 1; d < 512; d <<= 1) {
        int a = (t >= d) ? offs[t - d] : 0;
        __syncthreads();
        offs[t] += a;
        __syncthreads();
    }
    if (t < NB && hist[t]) base[t] = bin_start[t] + atomicAdd(&bin_cursor[t], hist[t]);
#pragma unroll
    for (int k = 0; k < SC_K; ++k) {
        int idx = t + k * SC_T;
        if (idx < nE) {
            int b = myBin[k];
            int pos = (offs[b] - hist[b]) + myRank[k];
            stage_p[pos] = myPack[k];
            stage_w[pos] = myW[k];
            stage_b[pos] = (unsigned short)b;
        }
    }
    __syncthreads();
    for (int p = t; p < nE; p += SC_T) {
        int b = stage_b[p];
        int g = base[b] + (p - (offs[b] - hist[b]));
        bp[g] = stage_p[p];
        bw[g] = stage_w[p];
    }
}

// ---------------- step 4: per-bin counting sort -> dense CSR + dinv ----------------
__global__ void csr_build(const int* __restrict__ bp, const float* __restrict__ bw,
                          const int* __restrict__ bin_start,
                          int* __restrict__ row_beg, int* __restrict__ row_cnt,
                          float* __restrict__ dinv,
                          int* __restrict__ fsrc, float* __restrict__ fw,
                          int N, int NB) {
    __shared__ int cnt[RNODES];
    __shared__ float wsum[RNODES];
    __shared__ int starts[RNODES];
    __shared__ int cur[RNODES];
    int b = blockIdx.x;
    int t = threadIdx.x;   // 512
    if (t < RNODES) { cnt[t] = 0; wsum[t] = 0.f; }
    __syncthreads();
    int beg = bin_start[b], end = bin_start[b + 1];
    for (int e = beg + t; e < end; e += 512) {
        int off = bp[e] & (RNODES - 1);
        atomicAdd(&cnt[off], 1);
        atomicAdd(&wsum[off], bw[e]);
    }
    __syncthreads();
    if (t < RNODES) starts[t] = cnt[t];
    __syncthreads();
    for (int d = 1; d < RNODES; d <<= 1) {
        int a = 0;
        if (t < RNODES && t >= d) a = starts[t - d];
        __syncthreads();
        if (t < RNODES) starts[t] += a;
        __syncthreads();
    }
    if (t < RNODES) {
        int ex = starts[t] - cnt[t];
        cur[t] = beg + ex;
        int node = (b << RBITS) + t;
        if (node < N) {
            row_beg[node] = beg + ex;
            row_cnt[node] = cnt[t];
            dinv[node] = rsqrtf(wsum[t] + 1.0f);   // +1 = self-loop weight
        }
    }
    __syncthreads();
    for (int e = beg + t; e < end; e += 512) {
        int p = bp[e];
        int slot = atomicAdd(&cur[p & (RNODES - 1)], 1);
        fsrc[slot] = p >> RBITS;
        fw[slot] = bw[e];
    }
}

// ---------------- MFMA GEMMs (split-bf16 3-product, near-fp32 accuracy) ----------------
// H1[N x 64] bf16 = X[N x 64] fp32 @ W[64 x 64] fp32
__global__ __launch_bounds__(256) void gemm1_mfma(const float* __restrict__ X,
                                                  const float* __restrict__ W,
                                                  unsigned short* __restrict__ H, int N) {
    int lane = threadIdx.x & 63;
    int wv = threadIdx.x >> 6;
    int quad = lane >> 4;
    int col = lane & 15;

    bf16x8 Bh[4][2], Bl[4][2];
#pragma unroll
    for (int nt = 0; nt < 4; ++nt)
#pragma unroll
        for (int kh = 0; kh < 2; ++kh)
#pragma unroll
            for (int j = 0; j < 8; ++j) {
                float wval = W[(kh * 32 + quad * 8 + j) * 64 + nt * 16 + col];
                unsigned hb = f2bf(wval);
                Bh[nt][kh][j] = (short)hb;
                Bl[nt][kh][j] = (short)f2bf(wval - bf2f(hb));
            }

#pragma unroll
    for (int rt = 0; rt < 4; ++rt) {
        int rb = blockIdx.x * 256 + wv * 64 + rt * 16;
        if (rb >= N) break;                       // wave-uniform
        int arow = rb + col;                      // col doubles as A's m index
        bf16x8 Ah[2], Al[2];
#pragma unroll
        for (int kh = 0; kh < 2; ++kh) {
            float xv[8];
            if (arow < N) {
                const float4* p = (const float4*)(X + (size_t)arow * 64 + kh * 32 + quad * 8);
                float4 f0 = p[0], f1 = p[1];
                xv[0] = f0.x; xv[1] = f0.y; xv[2] = f0.z; xv[3] = f0.w;
                xv[4] = f1.x; xv[5] = f1.y; xv[6] = f1.z; xv[7] = f1.w;
            } else {
#pragma unroll
                for (int j = 0; j < 8; ++j) xv[j] = 0.f;
            }
#pragma unroll
            for (int j = 0; j < 8; ++j) {
                unsigned hb = f2bf(xv[j]);
                Ah[kh][j] = (short)hb;
                Al[kh][j] = (short)f2bf(xv[j] - bf2f(hb));
            }
        }
        f32x4 acc[4] = {{0,0,0,0},{0,0,0,0},{0,0,0,0},{0,0,0,0}};
#pragma unroll
        for (int nt = 0; nt < 4; ++nt)
#pragma unroll
            for (int kh = 0; kh < 2; ++kh) {
                acc[nt] = __builtin_amdgcn_mfma_f32_16x16x32_bf16(Ah[kh], Bh[nt][kh], acc[nt], 0, 0, 0);
                acc[nt] = __builtin_amdgcn_mfma_f32_16x16x32_bf16(Al[kh], Bh[nt][kh], acc[nt], 0, 0, 0);
                acc[nt] = __builtin_amdgcn_mfma_f32_16x16x32_bf16(Ah[kh], Bl[nt][kh], acc[nt], 0, 0, 0);
            }
#pragma unroll
        for (int nt = 0; nt < 4; ++nt)
#pragma unroll
            for (int r = 0; r < 4; ++r) {
                int row = rb + quad * 4 + r;
                if (row < N)
                    H[(size_t)row * 64 + nt * 16 + col] = (unsigned short)f2bf(acc[nt][r]);
            }
    }
}

// H2[N x 32] bf16 = relu(X[N x 64] fp32) @ W[64 x 32] fp32
__global__ __launch_bounds__(256) void gemm2_mfma(const float* __restrict__ X,
                                                  const float* __restrict__ W,
                                                  unsigned short* __restrict__ H, int N) {
    int lane = threadIdx.x & 63;
    int wv = threadIdx.x >> 6;
    int quad = lane >> 4;
    int col = lane & 15;

    bf16x8 Bh[2][2], Bl[2][2];
#pragma unroll
    for (int nt = 0; nt < 2; ++nt)
#pragma unroll
        for (int kh = 0; kh < 2; ++kh)
#pragma unroll
            for (int j = 0; j < 8; ++j) {
                float wval = W[(kh * 32 + quad * 8 + j) * 32 + nt * 16 + col];
                unsigned hb = f2bf(wval);
                Bh[nt][kh][j] = (short)hb;
                Bl[nt][kh][j] = (short)f2bf(wval - bf2f(hb));
            }

#pragma unroll
    for (int rt = 0; rt < 4; ++rt) {
        int rb = blockIdx.x * 256 + wv * 64 + rt * 16;
        if (rb >= N) break;
        int arow = rb + col;
        bf16x8 Ah[2], Al[2];
#pragma unroll
        for (int kh = 0; kh < 2; ++kh) {
            float xv[8];
            if (arow < N) {
                const float4* p = (const float4*)(X + (size_t)arow * 64 + kh * 32 + quad * 8);
                float4 f0 = p[0], f1 = p[1];
                xv[0] = f0.x; xv[1] = f0.y; xv[2] = f0.z; xv[3] = f0.w;
                xv[4] = f1.x; xv[5] = f1.y; xv[6] = f1.z; xv[7] = f1.w;
            } else {
#pragma unroll
                for (int j = 0; j < 8; ++j) xv[j] = 0.f;
            }
#pragma unroll
            for (int j = 0; j < 8; ++j) {
                float xr = fmaxf(xv[j], 0.f);     // fused relu
                unsigned hb = f2bf(xr);
                Ah[kh][j] = (short)hb;
                Al[kh][j] = (short)f2bf(xr - bf2f(hb));
            }
        }
        f32x4 acc[2] = {{0,0,0,0},{0,0,0,0}};
#pragma unroll
        for (int nt = 0; nt < 2; ++nt)
#pragma unroll
            for (int kh = 0; kh < 2; ++kh) {
                acc[nt] = __builtin_amdgcn_mfma_f32_16x16x32_bf16(Ah[kh], Bh[nt][kh], acc[nt], 0, 0, 0);
                acc[nt] = __builtin_amdgcn_mfma_f32_16x16x32_bf16(Al[kh], Bh[nt][kh], acc[nt], 0, 0, 0);
                acc[nt] = __builtin_amdgcn_mfma_f32_16x16x32_bf16(Ah[kh], Bl[nt][kh], acc[nt], 0, 0, 0);
            }
#pragma unroll
        for (int nt = 0; nt < 2; ++nt)
#pragma unroll
            for (int r = 0; r < 4; ++r) {
                int row = rb + quad * 4 + r;
                if (row < N)
                    H[(size_t)row * 32 + nt * 16 + col] = (unsigned short)f2bf(acc[nt][r]);
            }
    }
}

// ---------------- aggregation: 1 node per 8-lane group, no cross-lane reduction ----------------
// 64 ch: row = 8 x uint4; lane c owns 8 channels of its group's node across ALL edges.
// 8 groups/wave x 2-unroll = 16 gathers in flight; zero shuffles; coalesced epilogue
// (consecutive groups = consecutive nodes).
__global__ void aggregate64(const unsigned* __restrict__ h, const int* __restrict__ row_beg,
                            const int* __restrict__ row_cnt, const int* __restrict__ fsrc,
                            const float* __restrict__ fw, const float* __restrict__ dinv,
                            const float* __restrict__ b, float* __restrict__ out, int N) {
    int t = threadIdx.x;
    int c = t & 7;                       // uint4 index in row (8 ch per lane)
    int i = blockIdx.x * 64 + (t >> 3);  // node per 8-lane group
    if (i >= N) return;
    int e = row_beg[i];
    int end = e + row_cnt[i];
    const uint4* h4 = (const uint4*)h;
    float acc[8];
#pragma unroll
    for (int j = 0; j < 8; ++j) acc[j] = 0.f;
    for (; e + 1 < end; e += 2) {
        int s0 = fsrc[e];
        int s1 = fsrc[e + 1];
        float n0 = fw[e] * dinv[s0];
        float n1 = fw[e + 1] * dinv[s1];
        uint4 v0 = h4[(size_t)s0 * 8 + c];
        uint4 v1 = h4[(size_t)s1 * 8 + c];
        acc[0] += n0 * bf_lo(v0.x) + n1 * bf_lo(v1.x);
        acc[1] += n0 * bf_hi(v0.x) + n1 * bf_hi(v1.x);
        acc[2] += n0 * bf_lo(v0.y) + n1 * bf_lo(v1.y);
        acc[3] += n0 * bf_hi(v0.y) + n1 * bf_hi(v1.y);
        acc[4] += n0 * bf_lo(v0.z) + n1 * bf_lo(v1.z);
        acc[5] += n0 * bf_hi(v0.z) + n1 * bf_hi(v1.z);
        acc[6] += n0 * bf_lo(v0.w) + n1 * bf_lo(v1.w);
        acc[7] += n0 * bf_hi(v0.w) + n1 * bf_hi(v1.w);
    }
    if (e < end) {
        int s0 = fsrc[e];
        float n0 = fw[e] * dinv[s0];
        uint4 v0 = h4[(size_t)s0 * 8 + c];
        acc[0] += n0 * bf_lo(v0.x);
        acc[1] += n0 * bf_hi(v0.x);
        acc[2] += n0 * bf_lo(v0.y);
        acc[3] += n0 * bf_hi(v0.y);
        acc[4] += n0 * bf_lo(v0.z);
        acc[5] += n0 * bf_hi(v0.z);
        acc[6] += n0 * bf_lo(v0.w);
        acc[7] += n0 * bf_hi(v0.w);
    }
    float di = dinv[i];
    uint4 hv = h4[(size_t)i * 8 + c];
    float hs[8] = {bf_lo(hv.x), bf_hi(hv.x), bf_lo(hv.y), bf_hi(hv.y),
                   bf_lo(hv.z), bf_hi(hv.z), bf_lo(hv.w), bf_hi(hv.w)};
    float4 b0 = ((const float4*)b)[c * 2];
    float4 b1 = ((const float4*)b)[c * 2 + 1];
    float4 o0, o1;
    o0.x = b0.x + di * (di * hs[0] + acc[0]);
    o0.y = b0.y + di * (di * hs[1] + acc[1]);
    o0.z = b0.z + di * (di * hs[2] + acc[2]);
    o0.w = b0.w + di * (di * hs[3] + acc[3]);
    o1.x = b1.x + di * (di * hs[4] + acc[4]);
    o1.y = b1.y + di * (di * hs[5] + acc[5]);
    o1.z = b1.z + di * (di * hs[6] + acc[6]);
    o1.w = b1.w + di * (di * hs[7] + acc[7]);
    float4* op = (float4*)(out + (size_t)i * 64 + c * 8);
    op[0] = o0;
    op[1] = o1;
}

// 32 ch: row = 4 x uint4; 1 node per 4-lane group, 16 groups/wave.
__global__ void aggregate32(const unsigned* __restrict__ h, const int* __restrict__ row_beg,
                            const int* __restrict__ row_cnt, const int* __restrict__ fsrc,
                            const float* __restrict__ fw, const float* __restrict__ dinv,
                            const float* __restrict__ b, float* __restrict__ out, int N) {
    int t = threadIdx.x;
    int c = t & 3;                        // uint4 index in row (8 ch per lane)
    int i = blockIdx.x * 128 + (t >> 2);  // node per 4-lane group
    if (i >= N) return;
    int e = row_beg[i];
    int end = e + row_cnt[i];
    const uint4* h4 = (const uint4*)h;
    float acc[8];
#pragma unroll
    for (int j = 0; j < 8; ++j) acc[j] = 0.f;
    for (; e + 1 < end; e += 2) {
        int s0 = fsrc[e];
        int s1 = fsrc[e + 1];
        float n0 = fw[e] * dinv[s0];
        float n1 = fw[e + 1] * dinv[s1];
        uint4 v0 = h4[(size_t)s0 * 4 + c];
        uint4 v1 = h4[(size_t)s1 * 4 + c];
        acc[0] += n0 * bf_lo(v0.x) + n1 * bf_lo(v1.x);
        acc[1] += n0 * bf_hi(v0.x) + n1 * bf_hi(v1.x);
        acc[2] += n0 * bf_lo(v0.y) + n1 * bf_lo(v1.y);
        acc[3] += n0 * bf_hi(v0.y) + n1 * bf_hi(v1.y);
        acc[4] += n0 * bf_lo(v0.z) + n1 * bf_lo(v1.z);
        acc[5] += n0 * bf_hi(v0.z) + n1 * bf_hi(v1.z);
        acc[6] += n0 * bf_lo(v0.w) + n1 * bf_lo(v1.w);
        acc[7] += n0 * bf_hi(v0.w) + n1 * bf_hi(v1.w);
    }
    if (e < end) {
        int s0 = fsrc[e];
        float n0 = fw[e] * dinv[s0];
        uint4 v0 = h4[(size_t)s0 * 4 + c];
        acc[0] += n0 * bf_lo(v0.x);
        acc[1] += n0 * bf_hi(v0.x);
        acc[2] += n0 * bf_lo(v0.y);
        acc[3] += n0 * bf_hi(v0.y);
        acc[4] += n0 * bf_lo(v0.z);
        acc[5] += n0 * bf_hi(v0.z);
        acc[6] += n0 * bf_lo(v0.w);
        acc[7] += n0 * bf_hi(v0.w);
    }
    float di = dinv[i];
    uint4 hv = h4[(size_t)i * 4 + c];
    float hs[8] = {bf_lo(hv.x), bf_hi(hv.x), bf_lo(hv.y), bf_hi(hv.y),
                   bf_lo(hv.z), bf_hi(hv.z), bf_lo(hv.w), bf_hi(hv.w)};
    float4 b0 = ((const float4*)b)[c * 2];
    float4 b1 = ((const float4*)b)[c * 2 + 1];
    float4 o0, o1;
    o0.x = b0.x + di * (di * hs[0] + acc[0]);
    o0.y = b0.y + di * (di * hs[1] + acc[1]);
    o0.z = b0.z + di * (di * hs[2] + acc[2]);
    o0.w = b0.w + di * (di * hs[3] + acc[3]);
    o1.x = b1.x + di * (di * hs[4] + acc[4]);
    o1.y = b1.y + di * (di * hs[5] + acc[5]);
    o1.z = b1.z + di * (di * hs[6] + acc[6]);
    o1.w = b1.w + di * (di * hs[7] + acc[7]);
    float4* op = (float4*)(out + (size_t)i * 32 + c * 8);
    op[0] = o0;
    op[1] = o1;
}

extern "C" void kernel_launch(void* const* d_in, const int* in_sizes, int n_in,
                              void* d_out, int out_size, void* d_ws, size_t ws_size,
                              hipStream_t stream) {
    const float* x  = (const float*)d_in[0];
    const int* eidx = (const int*)d_in[1];      // int64 in reference -> int32 on device
    const float* w  = (const float*)d_in[2];
    const float* W1 = (const float*)d_in[3];
    const float* b1 = (const float*)d_in[4];
    const float* W2 = (const float*)d_in[5];
    const float* b2 = (const float*)d_in[6];
    float* out = (float*)d_out;

    const int E = in_sizes[2];
    const int N = in_sizes[0] / 64;
    const int* src = eidx;
    const int* dst = eidx + E;
    const int NB = ceil_div(N, RNODES);          // 391 bins (must be <= 512)

    // workspace carve-up (256B-aligned)
    char* ws = (char*)d_ws;
    size_t off = 0;
    auto alloc = [&](size_t bytes) -> void* {
        void* p = ws + off;
        off = (off + bytes + 255) & ~(size_t)255;
        return p;
    };
    int*      bin_sizes  = (int*)alloc((size_t)NB * 4);
    int*      bin_cursor = (int*)alloc((size_t)NB * 4);
    int*      bin_start  = (int*)alloc((size_t)(NB + 1) * 4);
    int*      bp         = (int*)alloc((size_t)E * 4);     // binned packed (src<<8)|dstoff
    float*    bw         = (float*)alloc((size_t)E * 4);   // binned weights
    int*      fsrc       = (int*)alloc((size_t)E * 4);     // final CSR src
    float*    fw         = (float*)alloc((size_t)E * 4);   // final CSR weight
    int*      row_beg    = (int*)alloc((size_t)N * 4);
    int*      row_cnt    = (int*)alloc((size_t)N * 4);
    float*    dinv       = (float*)alloc((size_t)N * 4);
    unsigned* h1         = (unsigned*)alloc((size_t)N * 32 * 4);  // bf16 N x 64
    unsigned* h2         = (unsigned*)alloc((size_t)N * 16 * 4);  // bf16 N x 32
    float*    out1       = (float*)alloc((size_t)N * 64 * 4);     // fp32 layer-1 output

    // build (no per-edge global atomics anywhere)
    zero_bins<<<1, 512, 0, stream>>>(bin_sizes, bin_cursor, NB);
    bin_count<<<96, 512, 0, stream>>>(dst, bin_sizes, NB, E);
    bin_scan<<<1, 512, 0, stream>>>(bin_sizes, bin_start, NB);
    bin_scatter<<<ceil_div(E, SC_E), SC_T, 0, stream>>>(src, dst, w, bin_cursor, bin_start,
                                                        bp, bw, NB, E);
    csr_build<<<NB, 512, 0, stream>>>(bp, bw, bin_start, row_beg, row_cnt, dinv, fsrc, fw, N, NB);

    // layer 1 (MFMA gemm -> bf16 table)
    gemm1_mfma<<<ceil_div(N, 256), 256, 0, stream>>>(x, W1, (unsigned short*)h1, N);
    aggregate64<<<ceil_div(N, 64), 512, 0, stream>>>(h1, row_beg, row_cnt, fsrc, fw, dinv, b1, out1, N);

    // layer 2 (fused relu + MFMA gemm -> bf16 table)
    gemm2_mfma<<<ceil_div(N, 256), 256, 0, stream>>>(out1, W2, (unsigned short*)h2, N);
    aggregate32<<<ceil_div(N, 128), 512, 0, stream>>>(h2, row_beg, row_cnt, fsrc, fw, dinv, b2, out, N);
}

// Round 10
// 210.420 us; speedup vs baseline: 8.1197x; 1.0331x over previous
//
#include <hip/hip_runtime.h>

static inline int ceil_div(long long a, long long b) { return (int)((a + b - 1) / b); }

// Node-range binning: bin = dst >> 8 (256 nodes per bin). N <= 131072 assumed (N=100000).
#define RBITS 8
#define RNODES 256
#define CNT_BLOCKS 96

typedef __attribute__((ext_vector_type(8))) short bf16x8;
typedef __attribute__((ext_vector_type(4))) float f32x4;

// bf16 helpers: pack with round-to-nearest-even, unpack via bit ops
__device__ inline unsigned f2bf(float f) {
    unsigned u = __float_as_uint(f);
    return (u + 0x7fffu + ((u >> 16) & 1u)) >> 16;
}
__device__ inline float bf2f(unsigned v) { return __uint_as_float(v << 16); }
__device__ inline float bf_lo(unsigned v) { return __uint_as_float(v << 16); }
__device__ inline float bf_hi(unsigned v) { return __uint_as_float(v & 0xffff0000u); }

// ---------------- step 1: per-bin edge counts, atomic-free ----------------
// each block writes its private histogram slice; no zeroing kernel needed.
__global__ void bin_count(const int* __restrict__ dst, int* __restrict__ hist_g,
                          int NB, int E) {
    __shared__ int hist[512];
    int t = threadIdx.x;
    hist[t] = 0;
    __syncthreads();
    // int4 vectorized grid-stride (E assumed %4==0 at this scale; tail handled below)
    int nvec = E >> 2;
    const int4* d4 = (const int4*)dst;
    for (int v = blockIdx.x * 512 + t; v < nvec; v += CNT_BLOCKS * 512) {
        int4 d = d4[v];
        atomicAdd(&hist[d.x >> RBITS], 1);
        atomicAdd(&hist[d.y >> RBITS], 1);
        atomicAdd(&hist[d.z >> RBITS], 1);
        atomicAdd(&hist[d.w >> RBITS], 1);
    }
    if (blockIdx.x == 0 && t < (E & 3))
        atomicAdd(&hist[dst[(nvec << 2) + t] >> RBITS], 1);
    __syncthreads();
    if (t < NB) hist_g[blockIdx.x * NB + t] = hist[t];
}

// ---------------- step 2: reduce partials + exclusive scan + cursor init ----------------
__global__ void bin_scan(const int* __restrict__ hist_g, int* __restrict__ bin_start,
                         int* __restrict__ bin_cursor, int NB) {
    __shared__ int s[512];
    int t = threadIdx.x;
    int v = 0;
    if (t < NB) {
        for (int k = 0; k < CNT_BLOCKS; ++k) v += hist_g[k * NB + t];
        bin_cursor[t] = 0;
    }
    s[t] = v;
    __syncthreads();
    for (int d = 1; d < 512; d <<= 1) {
        int a = (t >= d) ? s[t - d] : 0;
        __syncthreads();
        s[t] += a;
        __syncthreads();
    }
    if (t < NB) bin_start[t] = s[t] - v;       // exclusive
    if (t == NB - 1) bin_start[NB] = s[t];     // total = E
}

// ---------------- step 3: partition edges into bins (LDS staging) ----------------
#define SC_T 512
#define SC_K 8
#define SC_E (SC_T * SC_K)   // 4096 edges per block
__global__ void bin_scatter(const int* __restrict__ src, const int* __restrict__ dst,
                            const float* __restrict__ w, int* __restrict__ bin_cursor,
                            const int* __restrict__ bin_start,
                            int* __restrict__ bp, float* __restrict__ bw,
                            int NB, int E) {
    __shared__ int hist[512];
    __shared__ int offs[512];               // inclusive scan of hist
    __shared__ int base[512];               // global write base per bin
    __shared__ int stage_p[SC_E];
    __shared__ float stage_w[SC_E];
    __shared__ unsigned short stage_b[SC_E]; // bin id per staged slot
    int t = threadIdx.x;
    hist[t] = 0;
    __syncthreads();
    int e0 = blockIdx.x * SC_E;
    int nE = E - e0; if (nE > SC_E) nE = SC_E;

    int myBin[SC_K], myRank[SC_K], myPack[SC_K];
    float myW[SC_K];
#pragma unroll
    for (int k = 0; k < SC_K; ++k) {
        int idx = t + k * SC_T;
        if (idx < nE) {
            int e = e0 + idx;
            int d = dst[e];
            int b = d >> RBITS;
            myBin[k] = b;
            myPack[k] = (src[e] << RBITS) | (d & (RNODES - 1));
            myW[k] = w[e];
            myRank[k] = atomicAdd(&hist[b], 1);
        }
    }
    __syncthreads();
    offs[t] = hist[t];
    __syncthreads();
    for (int d = 1; d < 512; d <<= 1) {
        int a = (t >= d) ? offs[t - d] : 0;
        __syncthreads();
        offs[t] += a;
        __syncthreads();
    }
    if (t < NB && hist[t]) base[t] = bin_start[t] + atomicAdd(&bin_cursor[t], hist[t]);
#pragma unroll
    for (int k = 0; k < SC_K; ++k) {
        int idx = t + k * SC_T;
        if (idx < nE) {
            int b = myBin[k];
            int pos = (offs[b] - hist[b]) + myRank[k];
            stage_p[pos] = myPack[k];
            stage_w[pos] = myW[k];
            stage_b[pos] = (unsigned short)b;
        }
    }
    __syncthreads();
    for (int p = t; p < nE; p += SC_T) {
        int b = stage_b[p];
        int g = base[b] + (p - (offs[b] - hist[b]));
        bp[g] = stage_p[p];
        bw[g] = stage_w[p];
    }
}

// ---------------- step 4: per-bin counting sort -> dense CSR + dinv ----------------
__global__ void csr_build(const int* __restrict__ bp, const float* __restrict__ bw,
                          const int* __restrict__ bin_start,
                          int* __restrict__ row_beg, int* __restrict__ row_cnt,
                          float* __restrict__ dinv,
                          int* __restrict__ fsrc, float* __restrict__ fw,
                          int N, int NB) {
    __shared__ int cnt[RNODES];
    __shared__ float wsum[RNODES];
    __shared__ int starts[RNODES];
    __shared__ int cur[RNODES];
    int b = blockIdx.x;
    int t = threadIdx.x;   // 512
    if (t < RNODES) { cnt[t] = 0; wsum[t] = 0.f; }
    __syncthreads();
    int beg = bin_start[b], end = bin_start[b + 1];
    for (int e = beg + t; e < end; e += 512) {
        int off = bp[e] & (RNODES - 1);
        atomicAdd(&cnt[off], 1);
        atomicAdd(&wsum[off], bw[e]);
    }
    __syncthreads();
    if (t < RNODES) starts[t] = cnt[t];
    __syncthreads();
    for (int d = 1; d < RNODES; d <<= 1) {
        int a = 0;
        if (t < RNODES && t >= d) a = starts[t - d];
        __syncthreads();
        if (t < RNODES) starts[t] += a;
        __syncthreads();
    }
    if (t < RNODES) {
        int ex = starts[t] - cnt[t];
        cur[t] = beg + ex;
        int node = (b << RBITS) + t;
        if (node < N) {
            row_beg[node] = beg + ex;
            row_cnt[node] = cnt[t];
            dinv[node] = rsqrtf(wsum[t] + 1.0f);   // +1 = self-loop weight
        }
    }
    __syncthreads();
    for (int e = beg + t; e < end; e += 512) {
        int p = bp[e];
        int slot = atomicAdd(&cur[p & (RNODES - 1)], 1);
        fsrc[slot] = p >> RBITS;
        fw[slot] = bw[e];
    }
}

// ---------------- MFMA GEMMs (split-bf16 3-product, near-fp32 accuracy) ----------------
// H1[N x 64] bf16 = X[N x 64] fp32 @ W[64 x 64] fp32
__global__ __launch_bounds__(256) void gemm1_mfma(const float* __restrict__ X,
                                                  const float* __restrict__ W,
                                                  unsigned short* __restrict__ H, int N) {
    int lane = threadIdx.x & 63;
    int wv = threadIdx.x >> 6;
    int quad = lane >> 4;
    int col = lane & 15;

    bf16x8 Bh[4][2], Bl[4][2];
#pragma unroll
    for (int nt = 0; nt < 4; ++nt)
#pragma unroll
        for (int kh = 0; kh < 2; ++kh)
#pragma unroll
            for (int j = 0; j < 8; ++j) {
                float wval = W[(kh * 32 + quad * 8 + j) * 64 + nt * 16 + col];
                unsigned hb = f2bf(wval);
                Bh[nt][kh][j] = (short)hb;
                Bl[nt][kh][j] = (short)f2bf(wval - bf2f(hb));
            }

#pragma unroll
    for (int rt = 0; rt < 4; ++rt) {
        int rb = blockIdx.x * 256 + wv * 64 + rt * 16;
        if (rb >= N) break;                       // wave-uniform
        int arow = rb + col;                      // col doubles as A's m index
        bf16x8 Ah[2], Al[2];
#pragma unroll
        for (int kh = 0; kh < 2; ++kh) {
            float xv[8];
            if (arow < N) {
                const float4* p = (const float4*)(X + (size_t)arow * 64 + kh * 32 + quad * 8);
                float4 f0 = p[0], f1 = p[1];
                xv[0] = f0.x; xv[1] = f0.y; xv[2] = f0.z; xv[3] = f0.w;
                xv[4] = f1.x; xv[5] = f1.y; xv[6] = f1.z; xv[7] = f1.w;
            } else {
#pragma unroll
                for (int j = 0; j < 8; ++j) xv[j] = 0.f;
            }
#pragma unroll
            for (int j = 0; j < 8; ++j) {
                unsigned hb = f2bf(xv[j]);
                Ah[kh][j] = (short)hb;
                Al[kh][j] = (short)f2bf(xv[j] - bf2f(hb));
            }
        }
        f32x4 acc[4] = {{0,0,0,0},{0,0,0,0},{0,0,0,0},{0,0,0,0}};
#pragma unroll
        for (int nt = 0; nt < 4; ++nt)
#pragma unroll
            for (int kh = 0; kh < 2; ++kh) {
                acc[nt] = __builtin_amdgcn_mfma_f32_16x16x32_bf16(Ah[kh], Bh[nt][kh], acc[nt], 0, 0, 0);
                acc[nt] = __builtin_amdgcn_mfma_f32_16x16x32_bf16(Al[kh], Bh[nt][kh], acc[nt], 0, 0, 0);
                acc[nt] = __builtin_amdgcn_mfma_f32_16x16x32_bf16(Ah[kh], Bl[nt][kh], acc[nt], 0, 0, 0);
            }
#pragma unroll
        for (int nt = 0; nt < 4; ++nt)
#pragma unroll
            for (int r = 0; r < 4; ++r) {
                int row = rb + quad * 4 + r;
                if (row < N)
                    H[(size_t)row * 64 + nt * 16 + col] = (unsigned short)f2bf(acc[nt][r]);
            }
    }
}

// H2[N x 32] bf16 = relu(X[N x 64] fp32) @ W[64 x 32] fp32
__global__ __launch_bounds__(256) void gemm2_mfma(const float* __restrict__ X,
                                                  const float* __restrict__ W,
                                                  unsigned short* __restrict__ H, int N) {
    int lane = threadIdx.x & 63;
    int wv = threadIdx.x >> 6;
    int quad = lane >> 4;
    int col = lane & 15;

    bf16x8 Bh[2][2], Bl[2][2];
#pragma unroll
    for (int nt = 0; nt < 2; ++nt)
#pragma unroll
        for (int kh = 0; kh < 2; ++kh)
#pragma unroll
            for (int j = 0; j < 8; ++j) {
                float wval = W[(kh * 32 + quad * 8 + j) * 32 + nt * 16 + col];
                unsigned hb = f2bf(wval);
                Bh[nt][kh][j] = (short)hb;
                Bl[nt][kh][j] = (short)f2bf(wval - bf2f(hb));
            }

#pragma unroll
    for (int rt = 0; rt < 4; ++rt) {
        int rb = blockIdx.x * 256 + wv * 64 + rt * 16;
        if (rb >= N) break;
        int arow = rb + col;
        bf16x8 Ah[2], Al[2];
#pragma unroll
        for (int kh = 0; kh < 2; ++kh) {
            float xv[8];
            if (arow < N) {
                const float4* p = (const float4*)(X + (size_t)arow * 64 + kh * 32 + quad * 8);
                float4 f0 = p[0], f1 = p[1];
                xv[0] = f0.x; xv[1] = f0.y; xv[2] = f0.z; xv[3] = f0.w;
                xv[4] = f1.x; xv[5] = f1.y; xv[6] = f1.z; xv[7] = f1.w;
            } else {
#pragma unroll
                for (int j = 0; j < 8; ++j) xv[j] = 0.f;
            }
#pragma unroll
            for (int j = 0; j < 8; ++j) {
                float xr = fmaxf(xv[j], 0.f);     // fused relu
                unsigned hb = f2bf(xr);
                Ah[kh][j] = (short)hb;
                Al[kh][j] = (short)f2bf(xr - bf2f(hb));
            }
        }
        f32x4 acc[2] = {{0,0,0,0},{0,0,0,0}};
#pragma unroll
        for (int nt = 0; nt < 2; ++nt)
#pragma unroll
            for (int kh = 0; kh < 2; ++kh) {
                acc[nt] = __builtin_amdgcn_mfma_f32_16x16x32_bf16(Ah[kh], Bh[nt][kh], acc[nt], 0, 0, 0);
                acc[nt] = __builtin_amdgcn_mfma_f32_16x16x32_bf16(Al[kh], Bh[nt][kh], acc[nt], 0, 0, 0);
                acc[nt] = __builtin_amdgcn_mfma_f32_16x16x32_bf16(Ah[kh], Bl[nt][kh], acc[nt], 0, 0, 0);
            }
#pragma unroll
        for (int nt = 0; nt < 2; ++nt)
#pragma unroll
            for (int r = 0; r < 4; ++r) {
                int row = rb + quad * 4 + r;
                if (row < N)
                    H[(size_t)row * 32 + nt * 16 + col] = (unsigned short)f2bf(acc[nt][r]);
            }
    }
}

// ---------------- aggregation: 1 node per 8-lane group, 4x unrolled gathers ----------------
__global__ void aggregate64(const unsigned* __restrict__ h, const int* __restrict__ row_beg,
                            const int* __restrict__ row_cnt, const int* __restrict__ fsrc,
                            const float* __restrict__ fw, const float* __restrict__ dinv,
                            const float* __restrict__ b, float* __restrict__ out, int N) {
    int t = threadIdx.x;
    int c = t & 7;                       // uint4 index in row (8 ch per lane)
    int i = blockIdx.x * 64 + (t >> 3);  // node per 8-lane group
    if (i >= N) return;
    int e = row_beg[i];
    int end = e + row_cnt[i];
    const uint4* h4 = (const uint4*)h;
    float acc[8];
#pragma unroll
    for (int j = 0; j < 8; ++j) acc[j] = 0.f;
    for (; e + 3 < end; e += 4) {
        int s0 = fsrc[e], s1 = fsrc[e + 1], s2 = fsrc[e + 2], s3 = fsrc[e + 3];
        float n0 = fw[e] * dinv[s0];
        float n1 = fw[e + 1] * dinv[s1];
        float n2 = fw[e + 2] * dinv[s2];
        float n3 = fw[e + 3] * dinv[s3];
        uint4 v0 = h4[(size_t)s0 * 8 + c];
        uint4 v1 = h4[(size_t)s1 * 8 + c];
        uint4 v2 = h4[(size_t)s2 * 8 + c];
        uint4 v3 = h4[(size_t)s3 * 8 + c];
        acc[0] += n0 * bf_lo(v0.x) + n1 * bf_lo(v1.x) + n2 * bf_lo(v2.x) + n3 * bf_lo(v3.x);
        acc[1] += n0 * bf_hi(v0.x) + n1 * bf_hi(v1.x) + n2 * bf_hi(v2.x) + n3 * bf_hi(v3.x);
        acc[2] += n0 * bf_lo(v0.y) + n1 * bf_lo(v1.y) + n2 * bf_lo(v2.y) + n3 * bf_lo(v3.y);
        acc[3] += n0 * bf_hi(v0.y) + n1 * bf_hi(v1.y) + n2 * bf_hi(v2.y) + n3 * bf_hi(v3.y);
        acc[4] += n0 * bf_lo(v0.z) + n1 * bf_lo(v1.z) + n2 * bf_lo(v2.z) + n3 * bf_lo(v3.z);
        acc[5] += n0 * bf_hi(v0.z) + n1 * bf_hi(v1.z) + n2 * bf_hi(v2.z) + n3 * bf_hi(v3.z);
        acc[6] += n0 * bf_lo(v0.w) + n1 * bf_lo(v1.w) + n2 * bf_lo(v2.w) + n3 * bf_lo(v3.w);
        acc[7] += n0 * bf_hi(v0.w) + n1 * bf_hi(v1.w) + n2 * bf_hi(v2.w) + n3 * bf_hi(v3.w);
    }
    for (; e < end; ++e) {
        int s0 = fsrc[e];
        float n0 = fw[e] * dinv[s0];
        uint4 v0 = h4[(size_t)s0 * 8 + c];
        acc[0] += n0 * bf_lo(v0.x);
        acc[1] += n0 * bf_hi(v0.x);
        acc[2] += n0 * bf_lo(v0.y);
        acc[3] += n0 * bf_hi(v0.y);
        acc[4] += n0 * bf_lo(v0.z);
        acc[5] += n0 * bf_hi(v0.z);
        acc[6] += n0 * bf_lo(v0.w);
        acc[7] += n0 * bf_hi(v0.w);
    }
    float di = dinv[i];
    uint4 hv = h4[(size_t)i * 8 + c];
    float hs[8] = {bf_lo(hv.x), bf_hi(hv.x), bf_lo(hv.y), bf_hi(hv.y),
                   bf_lo(hv.z), bf_hi(hv.z), bf_lo(hv.w), bf_hi(hv.w)};
    float4 b0 = ((const float4*)b)[c * 2];
    float4 b1 = ((const float4*)b)[c * 2 + 1];
    float4 o0, o1;
    o0.x = b0.x + di * (di * hs[0] + acc[0]);
    o0.y = b0.y + di * (di * hs[1] + acc[1]);
    o0.z = b0.z + di * (di * hs[2] + acc[2]);
    o0.w = b0.w + di * (di * hs[3] + acc[3]);
    o1.x = b1.x + di * (di * hs[4] + acc[4]);
    o1.y = b1.y + di * (di * hs[5] + acc[5]);
    o1.z = b1.z + di * (di * hs[6] + acc[6]);
    o1.w = b1.w + di * (di * hs[7] + acc[7]);
    float4* op = (float4*)(out + (size_t)i * 64 + c * 8);
    op[0] = o0;
    op[1] = o1;
}

// 32 ch: row = 4 x uint4; 1 node per 4-lane group, 4x unrolled
__global__ void aggregate32(const unsigned* __restrict__ h, const int* __restrict__ row_beg,
                            const int* __restrict__ row_cnt, const int* __restrict__ fsrc,
                            const float* __restrict__ fw, const float* __restrict__ dinv,
                            const float* __restrict__ b, float* __restrict__ out, int N) {
    int t = threadIdx.x;
    int c = t & 3;                        // uint4 index in row (8 ch per lane)
    int i = blockIdx.x * 128 + (t >> 2);  // node per 4-lane group
    if (i >= N) return;
    int e = row_beg[i];
    int end = e + row_cnt[i];
    const uint4* h4 = (const uint4*)h;
    float acc[8];
#pragma unroll
    for (int j = 0; j < 8; ++j) acc[j] = 0.f;
    for (; e + 3 < end; e += 4) {
        int s0 = fsrc[e], s1 = fsrc[e + 1], s2 = fsrc[e + 2], s3 = fsrc[e + 3];
        float n0 = fw[e] * dinv[s0];
        float n1 = fw[e + 1] * dinv[s1];
        float n2 = fw[e + 2] * dinv[s2];
        float n3 = fw[e + 3] * dinv[s3];
        uint4 v0 = h4[(size_t)s0 * 4 + c];
        uint4 v1 = h4[(size_t)s1 * 4 + c];
        uint4 v2 = h4[(size_t)s2 * 4 + c];
        uint4 v3 = h4[(size_t)s3 * 4 + c];
        acc[0] += n0 * bf_lo(v0.x) + n1 * bf_lo(v1.x) + n2 * bf_lo(v2.x) + n3 * bf_lo(v3.x);
        acc[1] += n0 * bf_hi(v0.x) + n1 * bf_hi(v1.x) + n2 * bf_hi(v2.x) + n3 * bf_hi(v3.x);
        acc[2] += n0 * bf_lo(v0.y) + n1 * bf_lo(v1.y) + n2 * bf_lo(v2.y) + n3 * bf_lo(v3.y);
        acc[3] += n0 * bf_hi(v0.y) + n1 * bf_hi(v1.y) + n2 * bf_hi(v2.y) + n3 * bf_hi(v3.y);
        acc[4] += n0 * bf_lo(v0.z) + n1 * bf_lo(v1.z) + n2 * bf_lo(v2.z) + n3 * bf_lo(v3.z);
        acc[5] += n0 * bf_hi(v0.z) + n1 * bf_hi(v1.z) + n2 * bf_hi(v2.z) + n3 * bf_hi(v3.z);
        acc[6] += n0 * bf_lo(v0.w) + n1 * bf_lo(v1.w) + n2 * bf_lo(v2.w) + n3 * bf_lo(v3.w);
        acc[7] += n0 * bf_hi(v0.w) + n1 * bf_hi(v1.w) + n2 * bf_hi(v2.w) + n3 * bf_hi(v3.w);
    }
    for (; e < end; ++e) {
        int s0 = fsrc[e];
        float n0 = fw[e] * dinv[s0];
        uint4 v0 = h4[(size_t)s0 * 4 + c];
        acc[0] += n0 * bf_lo(v0.x);
        acc[1] += n0 * bf_hi(v0.x);
        acc[2] += n0 * bf_lo(v0.y);
        acc[3] += n0 * bf_hi(v0.y);
        acc[4] += n0 * bf_lo(v0.z);
        acc[5] += n0 * bf_hi(v0.z);
        acc[6] += n0 * bf_lo(v0.w);
        acc[7] += n0 * bf_hi(v0.w);
    }
    float di = dinv[i];
    uint4 hv = h4[(size_t)i * 4 + c];
    float hs[8] = {bf_lo(hv.x), bf_hi(hv.x), bf_lo(hv.y), bf_hi(hv.y),
                   bf_lo(hv.z), bf_hi(hv.z), bf_lo(hv.w), bf_hi(hv.w)};
    float4 b0 = ((const float4*)b)[c * 2];
    float4 b1 = ((const float4*)b)[c * 2 + 1];
    float4 o0, o1;
    o0.x = b0.x + di * (di * hs[0] + acc[0]);
    o0.y = b0.y + di * (di * hs[1] + acc[1]);
    o0.z = b0.z + di * (di * hs[2] + acc[2]);
    o0.w = b0.w + di * (di * hs[3] + acc[3]);
    o1.x = b1.x + di * (di * hs[4] + acc[4]);
    o1.y = b1.y + di * (di * hs[5] + acc[5]);
    o1.z = b1.z + di * (di * hs[6] + acc[6]);
    o1.w = b1.w + di * (di * hs[7] + acc[7]);
    float4* op = (float4*)(out + (size_t)i * 32 + c * 8);
    op[0] = o0;
    op[1] = o1;
}

extern "C" void kernel_launch(void* const* d_in, const int* in_sizes, int n_in,
                              void* d_out, int out_size, void* d_ws, size_t ws_size,
                              hipStream_t stream) {
    const float* x  = (const float*)d_in[0];
    const int* eidx = (const int*)d_in[1];      // int64 in reference -> int32 on device
    const float* w  = (const float*)d_in[2];
    const float* W1 = (const float*)d_in[3];
    const float* b1 = (const float*)d_in[4];
    const float* W2 = (const float*)d_in[5];
    const float* b2 = (const float*)d_in[6];
    float* out = (float*)d_out;

    const int E = in_sizes[2];
    const int N = in_sizes[0] / 64;
    const int* src = eidx;
    const int* dst = eidx + E;
    const int NB = ceil_div(N, RNODES);          // 391 bins (must be <= 512)

    // workspace carve-up (256B-aligned)
    char* ws = (char*)d_ws;
    size_t off = 0;
    auto alloc = [&](size_t bytes) -> void* {
        void* p = ws + off;
        off = (off + bytes + 255) & ~(size_t)255;
        return p;
    };
    int*      hist_g     = (int*)alloc((size_t)CNT_BLOCKS * NB * 4);  // per-block histograms
    int*      bin_cursor = (int*)alloc((size_t)NB * 4);
    int*      bin_start  = (int*)alloc((size_t)(NB + 1) * 4);
    int*      bp         = (int*)alloc((size_t)E * 4);     // binned packed (src<<8)|dstoff
    float*    bw         = (float*)alloc((size_t)E * 4);   // binned weights
    int*      fsrc       = (int*)alloc((size_t)E * 4);     // final CSR src
    float*    fw         = (float*)alloc((size_t)E * 4);   // final CSR weight
    int*      row_beg    = (int*)alloc((size_t)N * 4);
    int*      row_cnt    = (int*)alloc((size_t)N * 4);
    float*    dinv       = (float*)alloc((size_t)N * 4);
    unsigned* h1         = (unsigned*)alloc((size_t)N * 32 * 4);  // bf16 N x 64
    unsigned* h2         = (unsigned*)alloc((size_t)N * 16 * 4);  // bf16 N x 32
    float*    out1       = (float*)alloc((size_t)N * 64 * 4);     // fp32 layer-1 output

    // build (no per-edge global atomics anywhere)
    bin_count<<<CNT_BLOCKS, 512, 0, stream>>>(dst, hist_g, NB, E);
    bin_scan<<<1, 512, 0, stream>>>(hist_g, bin_start, bin_cursor, NB);
    bin_scatter<<<ceil_div(E, SC_E), SC_T, 0, stream>>>(src, dst, w, bin_cursor, bin_start,
                                                        bp, bw, NB, E);
    csr_build<<<NB, 512, 0, stream>>>(bp, bw, bin_start, row_beg, row_cnt, dinv, fsrc, fw, N, NB);

    // layer 1 (MFMA gemm -> bf16 table)
    gemm1_mfma<<<ceil_div(N, 256), 256, 0, stream>>>(x, W1, (unsigned short*)h1, N);
    aggregate64<<<ceil_div(N, 64), 512, 0, stream>>>(h1, row_beg, row_cnt, fsrc, fw, dinv, b1, out1, N);

    // layer 2 (fused relu + MFMA gemm -> bf16 table)
    gemm2_mfma<<<ceil_div(N, 256), 256, 0, stream>>>(out1, W2, (unsigned short*)h2, N);
    aggregate32<<<ceil_div(N, 128), 512, 0, stream>>>(h2, row_beg, row_cnt, fsrc, fw, dinv, b2, out, N);
}

// Round 11
// 201.485 us; speedup vs baseline: 8.4798x; 1.0443x over previous
//
#include <hip/hip_runtime.h>

static inline int ceil_div(long long a, long long b) { return (int)((a + b - 1) / b); }

// Node-range binning: bin = dst >> 8 (256 nodes per bin). N <= 131072 assumed (N=100000).
#define RBITS 8
#define RNODES 256
#define CNT_BLOCKS 96

typedef __attribute__((ext_vector_type(8))) short bf16x8;
typedef __attribute__((ext_vector_type(4))) float f32x4;

// bf16 helpers: pack with round-to-nearest-even, unpack via bit ops
__device__ inline unsigned f2bf(float f) {
    unsigned u = __float_as_uint(f);
    return (u + 0x7fffu + ((u >> 16) & 1u)) >> 16;
}
__device__ inline unsigned pack2(float a, float b) { return f2bf(a) | (f2bf(b) << 16); }
__device__ inline float bf2f(unsigned v) { return __uint_as_float(v << 16); }
__device__ inline float bf_lo(unsigned v) { return __uint_as_float(v << 16); }
__device__ inline float bf_hi(unsigned v) { return __uint_as_float(v & 0xffff0000u); }

// ---------------- step 1: per-bin edge counts, atomic-free ----------------
__global__ void bin_count(const int* __restrict__ dst, int* __restrict__ hist_g,
                          int NB, int E) {
    __shared__ int hist[512];
    int t = threadIdx.x;
    hist[t] = 0;
    __syncthreads();
    int nvec = E >> 2;
    const int4* d4 = (const int4*)dst;
    for (int v = blockIdx.x * 512 + t; v < nvec; v += CNT_BLOCKS * 512) {
        int4 d = d4[v];
        atomicAdd(&hist[d.x >> RBITS], 1);
        atomicAdd(&hist[d.y >> RBITS], 1);
        atomicAdd(&hist[d.z >> RBITS], 1);
        atomicAdd(&hist[d.w >> RBITS], 1);
    }
    if (blockIdx.x == 0 && t < (E & 3))
        atomicAdd(&hist[dst[(nvec << 2) + t] >> RBITS], 1);
    __syncthreads();
    if (t < NB) hist_g[blockIdx.x * NB + t] = hist[t];
}

// ---------------- step 2: reduce partials + exclusive scan + cursor init ----------------
__global__ void bin_scan(const int* __restrict__ hist_g, int* __restrict__ bin_start,
                         int* __restrict__ bin_cursor, int NB) {
    __shared__ int s[512];
    int t = threadIdx.x;
    int v = 0;
    if (t < NB) {
        for (int k = 0; k < CNT_BLOCKS; ++k) v += hist_g[k * NB + t];
        bin_cursor[t] = 0;
    }
    s[t] = v;
    __syncthreads();
    for (int d = 1; d < 512; d <<= 1) {
        int a = (t >= d) ? s[t - d] : 0;
        __syncthreads();
        s[t] += a;
        __syncthreads();
    }
    if (t < NB) bin_start[t] = s[t] - v;       // exclusive
    if (t == NB - 1) bin_start[NB] = s[t];     // total = E
}

// ---------------- step 3: partition edges into bins (LDS staging) ----------------
#define SC_T 512
#define SC_K 8
#define SC_E (SC_T * SC_K)   // 4096 edges per block
__global__ void bin_scatter(const int* __restrict__ src, const int* __restrict__ dst,
                            const float* __restrict__ w, int* __restrict__ bin_cursor,
                            const int* __restrict__ bin_start,
                            int* __restrict__ bp, float* __restrict__ bw,
                            int NB, int E) {
    __shared__ int hist[512];
    __shared__ int offs[512];               // inclusive scan of hist
    __shared__ int base[512];               // global write base per bin
    __shared__ int stage_p[SC_E];
    __shared__ float stage_w[SC_E];
    __shared__ unsigned short stage_b[SC_E]; // bin id per staged slot
    int t = threadIdx.x;
    hist[t] = 0;
    __syncthreads();
    int e0 = blockIdx.x * SC_E;
    int nE = E - e0; if (nE > SC_E) nE = SC_E;

    int myBin[SC_K], myRank[SC_K], myPack[SC_K];
    float myW[SC_K];
#pragma unroll
    for (int k = 0; k < SC_K; ++k) {
        int idx = t + k * SC_T;
        if (idx < nE) {
            int e = e0 + idx;
            int d = dst[e];
            int b = d >> RBITS;
            myBin[k] = b;
            myPack[k] = (src[e] << RBITS) | (d & (RNODES - 1));
            myW[k] = w[e];
            myRank[k] = atomicAdd(&hist[b], 1);
        }
    }
    __syncthreads();
    offs[t] = hist[t];
    __syncthreads();
    for (int d = 1; d < 512; d <<= 1) {
        int a = (t >= d) ? offs[t - d] : 0;
        __syncthreads();
        offs[t] += a;
        __syncthreads();
    }
    if (t < NB && hist[t]) base[t] = bin_start[t] + atomicAdd(&bin_cursor[t], hist[t]);
#pragma unroll
    for (int k = 0; k < SC_K; ++k) {
        int idx = t + k * SC_T;
        if (idx < nE) {
            int b = myBin[k];
            int pos = (offs[b] - hist[b]) + myRank[k];
            stage_p[pos] = myPack[k];
            stage_w[pos] = myW[k];
            stage_b[pos] = (unsigned short)b;
        }
    }
    __syncthreads();
    for (int p = t; p < nE; p += SC_T) {
        int b = stage_b[p];
        int g = base[b] + (p - (offs[b] - hist[b]));
        bp[g] = stage_p[p];
        bw[g] = stage_w[p];
    }
}

// ---------------- step 4a: per-bin degree histogram -> row_beg / row_cnt / dinv ----------------
__global__ void deg_csr(const int* __restrict__ bp, const float* __restrict__ bw,
                        const int* __restrict__ bin_start,
                        int* __restrict__ row_beg, int* __restrict__ row_cnt,
                        float* __restrict__ dinv, int N) {
    __shared__ int cnt[RNODES];
    __shared__ float wsum[RNODES];
    __shared__ int starts[RNODES];
    int b = blockIdx.x;
    int t = threadIdx.x;   // 512
    if (t < RNODES) { cnt[t] = 0; wsum[t] = 0.f; }
    __syncthreads();
    int beg = bin_start[b], end = bin_start[b + 1];
    for (int e = beg + t; e < end; e += 512) {
        int off = bp[e] & (RNODES - 1);
        atomicAdd(&cnt[off], 1);
        atomicAdd(&wsum[off], bw[e]);
    }
    __syncthreads();
    if (t < RNODES) starts[t] = cnt[t];
    __syncthreads();
    for (int d = 1; d < RNODES; d <<= 1) {
        int a = 0;
        if (t < RNODES && t >= d) a = starts[t - d];
        __syncthreads();
        if (t < RNODES) starts[t] += a;
        __syncthreads();
    }
    if (t < RNODES) {
        int node = (b << RBITS) + t;
        if (node < N) {
            row_beg[node] = beg + (starts[t] - cnt[t]);
            row_cnt[node] = cnt[t];
            dinv[node] = rsqrtf(wsum[t] + 1.0f);   // +1 = self-loop weight
        }
    }
}

// ---------------- step 4b: scatter into dense CSR with dinv[src] folded ----------------
__global__ void csr_scatter(const int* __restrict__ bp, const float* __restrict__ bw,
                            const int* __restrict__ bin_start, const int* __restrict__ row_beg,
                            const float* __restrict__ dinv, uint2* __restrict__ ew, int N) {
    __shared__ int cur[RNODES];
    int b = blockIdx.x;
    int t = threadIdx.x;   // 512
    if (t < RNODES) {
        int node = (b << RBITS) + t;
        cur[t] = (node < N) ? row_beg[node] : 0;
    }
    __syncthreads();
    int beg = bin_start[b], end = bin_start[b + 1];
    for (int e = beg + t; e < end; e += 512) {
        int p = bp[e];
        int s = p >> RBITS;
        int slot = atomicAdd(&cur[p & (RNODES - 1)], 1);
        uint2 v;
        v.x = (unsigned)s;
        v.y = __float_as_uint(bw[e] * dinv[s]);   // fold dinv[src] once, here
        ew[slot] = v;
    }
}

// ---------------- MFMA GEMMs ----------------
// H1[N x 64] bf16 = X[N x 64] fp32 @ W[64 x 64] fp32   (split-bf16 3-product)
__global__ __launch_bounds__(256) void gemm1_mfma(const float* __restrict__ X,
                                                  const float* __restrict__ W,
                                                  unsigned short* __restrict__ H, int N) {
    int lane = threadIdx.x & 63;
    int wv = threadIdx.x >> 6;
    int quad = lane >> 4;
    int col = lane & 15;

    bf16x8 Bh[4][2], Bl[4][2];
#pragma unroll
    for (int nt = 0; nt < 4; ++nt)
#pragma unroll
        for (int kh = 0; kh < 2; ++kh)
#pragma unroll
            for (int j = 0; j < 8; ++j) {
                float wval = W[(kh * 32 + quad * 8 + j) * 64 + nt * 16 + col];
                unsigned hb = f2bf(wval);
                Bh[nt][kh][j] = (short)hb;
                Bl[nt][kh][j] = (short)f2bf(wval - bf2f(hb));
            }

#pragma unroll
    for (int rt = 0; rt < 4; ++rt) {
        int rb = blockIdx.x * 256 + wv * 64 + rt * 16;
        if (rb >= N) break;                       // wave-uniform
        int arow = rb + col;
        bf16x8 Ah[2], Al[2];
#pragma unroll
        for (int kh = 0; kh < 2; ++kh) {
            float xv[8];
            if (arow < N) {
                const float4* p = (const float4*)(X + (size_t)arow * 64 + kh * 32 + quad * 8);
                float4 f0 = p[0], f1 = p[1];
                xv[0] = f0.x; xv[1] = f0.y; xv[2] = f0.z; xv[3] = f0.w;
                xv[4] = f1.x; xv[5] = f1.y; xv[6] = f1.z; xv[7] = f1.w;
            } else {
#pragma unroll
                for (int j = 0; j < 8; ++j) xv[j] = 0.f;
            }
#pragma unroll
            for (int j = 0; j < 8; ++j) {
                unsigned hb = f2bf(xv[j]);
                Ah[kh][j] = (short)hb;
                Al[kh][j] = (short)f2bf(xv[j] - bf2f(hb));
            }
        }
        f32x4 acc[4] = {{0,0,0,0},{0,0,0,0},{0,0,0,0},{0,0,0,0}};
#pragma unroll
        for (int nt = 0; nt < 4; ++nt)
#pragma unroll
            for (int kh = 0; kh < 2; ++kh) {
                acc[nt] = __builtin_amdgcn_mfma_f32_16x16x32_bf16(Ah[kh], Bh[nt][kh], acc[nt], 0, 0, 0);
                acc[nt] = __builtin_amdgcn_mfma_f32_16x16x32_bf16(Al[kh], Bh[nt][kh], acc[nt], 0, 0, 0);
                acc[nt] = __builtin_amdgcn_mfma_f32_16x16x32_bf16(Ah[kh], Bl[nt][kh], acc[nt], 0, 0, 0);
            }
#pragma unroll
        for (int nt = 0; nt < 4; ++nt)
#pragma unroll
            for (int r = 0; r < 4; ++r) {
                int row = rb + quad * 4 + r;
                if (row < N)
                    H[(size_t)row * 64 + nt * 16 + col] = (unsigned short)f2bf(acc[nt][r]);
            }
    }
}

// H2[N x 32] bf16 = Xb[N x 64] bf16 (relu already applied) @ W[64 x 32] fp32
// A is exact bf16 -> only 2 products (A*Bh + A*Bl).
__global__ __launch_bounds__(256) void gemm2_mfma(const unsigned short* __restrict__ Xb,
                                                  const float* __restrict__ W,
                                                  unsigned short* __restrict__ H, int N) {
    int lane = threadIdx.x & 63;
    int wv = threadIdx.x >> 6;
    int quad = lane >> 4;
    int col = lane & 15;

    bf16x8 Bh[2][2], Bl[2][2];
#pragma unroll
    for (int nt = 0; nt < 2; ++nt)
#pragma unroll
        for (int kh = 0; kh < 2; ++kh)
#pragma unroll
            for (int j = 0; j < 8; ++j) {
                float wval = W[(kh * 32 + quad * 8 + j) * 32 + nt * 16 + col];
                unsigned hb = f2bf(wval);
                Bh[nt][kh][j] = (short)hb;
                Bl[nt][kh][j] = (short)f2bf(wval - bf2f(hb));
            }

#pragma unroll
    for (int rt = 0; rt < 4; ++rt) {
        int rb = blockIdx.x * 256 + wv * 64 + rt * 16;
        if (rb >= N) break;
        int arow = rb + col;
        bf16x8 A[2];
#pragma unroll
        for (int kh = 0; kh < 2; ++kh) {
            if (arow < N) {
                const bf16x8* p = (const bf16x8*)(Xb + (size_t)arow * 64 + kh * 32 + quad * 8);
                A[kh] = *p;                        // already bf16 — exact
            } else {
                A[kh] = bf16x8{0,0,0,0,0,0,0,0};
            }
        }
        f32x4 acc[2] = {{0,0,0,0},{0,0,0,0}};
#pragma unroll
        for (int nt = 0; nt < 2; ++nt)
#pragma unroll
            for (int kh = 0; kh < 2; ++kh) {
                acc[nt] = __builtin_amdgcn_mfma_f32_16x16x32_bf16(A[kh], Bh[nt][kh], acc[nt], 0, 0, 0);
                acc[nt] = __builtin_amdgcn_mfma_f32_16x16x32_bf16(A[kh], Bl[nt][kh], acc[nt], 0, 0, 0);
            }
#pragma unroll
        for (int nt = 0; nt < 2; ++nt)
#pragma unroll
            for (int r = 0; r < 4; ++r) {
                int row = rb + quad * 4 + r;
                if (row < N)
                    H[(size_t)row * 32 + nt * 16 + col] = (unsigned short)f2bf(acc[nt][r]);
            }
    }
}

// ---------------- aggregation: 1 node per 8-lane group, packed uint2 edges ----------------
// Layer 1: bf16 h1 in, bf16 out (relu fused). Edge coeff = w*dinv[src] pre-folded.
__global__ void aggregate64(const unsigned* __restrict__ h, const int* __restrict__ row_beg,
                            const int* __restrict__ row_cnt, const uint2* __restrict__ ew,
                            const float* __restrict__ dinv, const float* __restrict__ b,
                            unsigned* __restrict__ outb, int N) {
    int t = threadIdx.x;
    int c = t & 7;                       // uint4 index in row (8 ch per lane)
    int i = blockIdx.x * 64 + (t >> 3);  // node per 8-lane group
    if (i >= N) return;
    int e = row_beg[i];
    int end = e + row_cnt[i];
    const uint4* h4 = (const uint4*)h;
    float acc[8];
#pragma unroll
    for (int j = 0; j < 8; ++j) acc[j] = 0.f;
    for (; e + 3 < end; e += 4) {
        uint2 e0 = ew[e], e1 = ew[e + 1], e2 = ew[e + 2], e3 = ew[e + 3];
        float n0 = __uint_as_float(e0.y);
        float n1 = __uint_as_float(e1.y);
        float n2 = __uint_as_float(e2.y);
        float n3 = __uint_as_float(e3.y);
        uint4 v0 = h4[(size_t)e0.x * 8 + c];
        uint4 v1 = h4[(size_t)e1.x * 8 + c];
        uint4 v2 = h4[(size_t)e2.x * 8 + c];
        uint4 v3 = h4[(size_t)e3.x * 8 + c];
        acc[0] += n0 * bf_lo(v0.x) + n1 * bf_lo(v1.x) + n2 * bf_lo(v2.x) + n3 * bf_lo(v3.x);
        acc[1] += n0 * bf_hi(v0.x) + n1 * bf_hi(v1.x) + n2 * bf_hi(v2.x) + n3 * bf_hi(v3.x);
        acc[2] += n0 * bf_lo(v0.y) + n1 * bf_lo(v1.y) + n2 * bf_lo(v2.y) + n3 * bf_lo(v3.y);
        acc[3] += n0 * bf_hi(v0.y) + n1 * bf_hi(v1.y) + n2 * bf_hi(v2.y) + n3 * bf_hi(v3.y);
        acc[4] += n0 * bf_lo(v0.z) + n1 * bf_lo(v1.z) + n2 * bf_lo(v2.z) + n3 * bf_lo(v3.z);
        acc[5] += n0 * bf_hi(v0.z) + n1 * bf_hi(v1.z) + n2 * bf_hi(v2.z) + n3 * bf_hi(v3.z);
        acc[6] += n0 * bf_lo(v0.w) + n1 * bf_lo(v1.w) + n2 * bf_lo(v2.w) + n3 * bf_lo(v3.w);
        acc[7] += n0 * bf_hi(v0.w) + n1 * bf_hi(v1.w) + n2 * bf_hi(v2.w) + n3 * bf_hi(v3.w);
    }
    for (; e < end; ++e) {
        uint2 e0 = ew[e];
        float n0 = __uint_as_float(e0.y);
        uint4 v0 = h4[(size_t)e0.x * 8 + c];
        acc[0] += n0 * bf_lo(v0.x);
        acc[1] += n0 * bf_hi(v0.x);
        acc[2] += n0 * bf_lo(v0.y);
        acc[3] += n0 * bf_hi(v0.y);
        acc[4] += n0 * bf_lo(v0.z);
        acc[5] += n0 * bf_hi(v0.z);
        acc[6] += n0 * bf_lo(v0.w);
        acc[7] += n0 * bf_hi(v0.w);
    }
    float di = dinv[i];
    uint4 hv = h4[(size_t)i * 8 + c];
    float hs[8] = {bf_lo(hv.x), bf_hi(hv.x), bf_lo(hv.y), bf_hi(hv.y),
                   bf_lo(hv.z), bf_hi(hv.z), bf_lo(hv.w), bf_hi(hv.w)};
    float4 b0 = ((const float4*)b)[c * 2];
    float4 b1 = ((const float4*)b)[c * 2 + 1];
    float o[8];
    o[0] = b0.x + di * (di * hs[0] + acc[0]);
    o[1] = b0.y + di * (di * hs[1] + acc[1]);
    o[2] = b0.z + di * (di * hs[2] + acc[2]);
    o[3] = b0.w + di * (di * hs[3] + acc[3]);
    o[4] = b1.x + di * (di * hs[4] + acc[4]);
    o[5] = b1.y + di * (di * hs[5] + acc[5]);
    o[6] = b1.z + di * (di * hs[6] + acc[6]);
    o[7] = b1.w + di * (di * hs[7] + acc[7]);
#pragma unroll
    for (int j = 0; j < 8; ++j) o[j] = fmaxf(o[j], 0.f);   // fused relu (out1 only feeds gemm2)
    uint4 ov;
    ov.x = pack2(o[0], o[1]);
    ov.y = pack2(o[2], o[3]);
    ov.z = pack2(o[4], o[5]);
    ov.w = pack2(o[6], o[7]);
    ((uint4*)outb)[(size_t)i * 8 + c] = ov;
}

// Layer 2: bf16 h2 in, fp32 final out. 1 node per 4-lane group.
__global__ void aggregate32(const unsigned* __restrict__ h, const int* __restrict__ row_beg,
                            const int* __restrict__ row_cnt, const uint2* __restrict__ ew,
                            const float* __restrict__ dinv, const float* __restrict__ b,
                            float* __restrict__ out, int N) {
    int t = threadIdx.x;
    int c = t & 3;                        // uint4 index in row (8 ch per lane)
    int i = blockIdx.x * 128 + (t >> 2);  // node per 4-lane group
    if (i >= N) return;
    int e = row_beg[i];
    int end = e + row_cnt[i];
    const uint4* h4 = (const uint4*)h;
    float acc[8];
#pragma unroll
    for (int j = 0; j < 8; ++j) acc[j] = 0.f;
    for (; e + 3 < end; e += 4) {
        uint2 e0 = ew[e], e1 = ew[e + 1], e2 = ew[e + 2], e3 = ew[e + 3];
        float n0 = __uint_as_float(e0.y);
        float n1 = __uint_as_float(e1.y);
        float n2 = __uint_as_float(e2.y);
        float n3 = __uint_as_float(e3.y);
        uint4 v0 = h4[(size_t)e0.x * 4 + c];
        uint4 v1 = h4[(size_t)e1.x * 4 + c];
        uint4 v2 = h4[(size_t)e2.x * 4 + c];
        uint4 v3 = h4[(size_t)e3.x * 4 + c];
        acc[0] += n0 * bf_lo(v0.x) + n1 * bf_lo(v1.x) + n2 * bf_lo(v2.x) + n3 * bf_lo(v3.x);
        acc[1] += n0 * bf_hi(v0.x) + n1 * bf_hi(v1.x) + n2 * bf_hi(v2.x) + n3 * bf_hi(v3.x);
        acc[2] += n0 * bf_lo(v0.y) + n1 * bf_lo(v1.y) + n2 * bf_lo(v2.y) + n3 * bf_lo(v3.y);
        acc[3] += n0 * bf_hi(v0.y) + n1 * bf_hi(v1.y) + n2 * bf_hi(v2.y) + n3 * bf_hi(v3.y);
        acc[4] += n0 * bf_lo(v0.z) + n1 * bf_lo(v1.z) + n2 * bf_lo(v2.z) + n3 * bf_lo(v3.z);
        acc[5] += n0 * bf_hi(v0.z) + n1 * bf_hi(v1.z) + n2 * bf_hi(v2.z) + n3 * bf_hi(v3.z);
        acc[6] += n0 * bf_lo(v0.w) + n1 * bf_lo(v1.w) + n2 * bf_lo(v2.w) + n3 * bf_lo(v3.w);
        acc[7] += n0 * bf_hi(v0.w) + n1 * bf_hi(v1.w) + n2 * bf_hi(v2.w) + n3 * bf_hi(v3.w);
    }
    for (; e < end; ++e) {
        uint2 e0 = ew[e];
        float n0 = __uint_as_float(e0.y);
        uint4 v0 = h4[(size_t)e0.x * 4 + c];
        acc[0] += n0 * bf_lo(v0.x);
        acc[1] += n0 * bf_hi(v0.x);
        acc[2] += n0 * bf_lo(v0.y);
        acc[3] += n0 * bf_hi(v0.y);
        acc[4] += n0 * bf_lo(v0.z);
        acc[5] += n0 * bf_hi(v0.z);
        acc[6] += n0 * bf_lo(v0.w);
        acc[7] += n0 * bf_hi(v0.w);
    }
    float di = dinv[i];
    uint4 hv = h4[(size_t)i * 4 + c];
    float hs[8] = {bf_lo(hv.x), bf_hi(hv.x), bf_lo(hv.y), bf_hi(hv.y),
                   bf_lo(hv.z), bf_hi(hv.z), bf_lo(hv.w), bf_hi(hv.w)};
    float4 b0 = ((const float4*)b)[c * 2];
    float4 b1 = ((const float4*)b)[c * 2 + 1];
    float4 o0, o1;
    o0.x = b0.x + di * (di * hs[0] + acc[0]);
    o0.y = b0.y + di * (di * hs[1] + acc[1]);
    o0.z = b0.z + di * (di * hs[2] + acc[2]);
    o0.w = b0.w + di * (di * hs[3] + acc[3]);
    o1.x = b1.x + di * (di * hs[4] + acc[4]);
    o1.y = b1.y + di * (di * hs[5] + acc[5]);
    o1.z = b1.z + di * (di * hs[6] + acc[6]);
    o1.w = b1.w + di * (di * hs[7] + acc[7]);
    float4* op = (float4*)(out + (size_t)i * 32 + c * 8);
    op[0] = o0;
    op[1] = o1;
}

extern "C" void kernel_launch(void* const* d_in, const int* in_sizes, int n_in,
                              void* d_out, int out_size, void* d_ws, size_t ws_size,
                              hipStream_t stream) {
    const float* x  = (const float*)d_in[0];
    const int* eidx = (const int*)d_in[1];      // int64 in reference -> int32 on device
    const float* w  = (const float*)d_in[2];
    const float* W1 = (const float*)d_in[3];
    const float* b1 = (const float*)d_in[4];
    const float* W2 = (const float*)d_in[5];
    const float* b2 = (const float*)d_in[6];
    float* out = (float*)d_out;

    const int E = in_sizes[2];
    const int N = in_sizes[0] / 64;
    const int* src = eidx;
    const int* dst = eidx + E;
    const int NB = ceil_div(N, RNODES);          // 391 bins (must be <= 512)

    // workspace carve-up (256B-aligned)
    char* ws = (char*)d_ws;
    size_t off = 0;
    auto alloc = [&](size_t bytes) -> void* {
        void* p = ws + off;
        off = (off + bytes + 255) & ~(size_t)255;
        return p;
    };
    int*      hist_g     = (int*)alloc((size_t)CNT_BLOCKS * NB * 4);
    int*      bin_cursor = (int*)alloc((size_t)NB * 4);
    int*      bin_start  = (int*)alloc((size_t)(NB + 1) * 4);
    int*      bp         = (int*)alloc((size_t)E * 4);      // binned packed (src<<8)|dstoff
    float*    bw         = (float*)alloc((size_t)E * 4);    // binned weights
    uint2*    ew         = (uint2*)alloc((size_t)E * 8);    // dense CSR {src, w*dinv[src]}
    int*      row_beg    = (int*)alloc((size_t)N * 4);
    int*      row_cnt    = (int*)alloc((size_t)N * 4);
    float*    dinv       = (float*)alloc((size_t)N * 4);
    unsigned* h1         = (unsigned*)alloc((size_t)N * 32 * 4);  // bf16 N x 64
    unsigned* out1b      = (unsigned*)alloc((size_t)N * 32 * 4);  // bf16 relu(out1), N x 64
    unsigned* h2         = (unsigned*)alloc((size_t)N * 16 * 4);  // bf16 N x 32

    // build (no per-edge global atomics anywhere)
    bin_count<<<CNT_BLOCKS, 512, 0, stream>>>(dst, hist_g, NB, E);
    bin_scan<<<1, 512, 0, stream>>>(hist_g, bin_start, bin_cursor, NB);
    bin_scatter<<<ceil_div(E, SC_E), SC_T, 0, stream>>>(src, dst, w, bin_cursor, bin_start,
                                                        bp, bw, NB, E);
    deg_csr<<<NB, 512, 0, stream>>>(bp, bw, bin_start, row_beg, row_cnt, dinv, N);
    csr_scatter<<<NB, 512, 0, stream>>>(bp, bw, bin_start, row_beg, dinv, ew, N);

    // layer 1 (MFMA gemm -> bf16 table; aggregate -> bf16 relu'd out1)
    gemm1_mfma<<<ceil_div(N, 256), 256, 0, stream>>>(x, W1, (unsigned short*)h1, N);
    aggregate64<<<ceil_div(N, 64), 512, 0, stream>>>(h1, row_beg, row_cnt, ew, dinv, b1, out1b, N);

    // layer 2 (bf16-A MFMA gemm -> bf16 table; aggregate -> fp32 out)
    gemm2_mfma<<<ceil_div(N, 256), 256, 0, stream>>>((const unsigned short*)out1b, W2,
                                                     (unsigned short*)h2, N);
    aggregate32<<<ceil_div(N, 128), 512, 0, stream>>>(h2, row_beg, row_cnt, ew, dinv, b2, out, N);
}